// Round 15
// baseline (135.673 us; speedup 1.0000x reference)
//
#include <hip/hip_runtime.h>
#include <hip/hip_bf16.h>
#include <string.h>

// GatedEncoderLayer: B=16, I=2048, J=1024, K=1024, F=32
// out[row,k] = sum_f [ (sum_j x[row,j]*Wy[j,f]) * Wx[row%I,f] ] * Wz[k,f]
constexpr int kI = 2048;
constexpr int kJ = 1024;
constexpr int kK = 1024;
constexpr int kF = 32;
constexpr int kRows = 16 * 2048;        // 32768

typedef __attribute__((ext_vector_type(8))) short short8v;
typedef __attribute__((ext_vector_type(4))) float f32x4;

__device__ inline unsigned short bf16_hi_bits(float v) {
    __hip_bfloat16 h = __float2bfloat16(v);      // RNE on gfx950
    unsigned short s;
    memcpy(&s, &h, 2);
    return s;
}
__device__ inline float bf16_bits_to_f(unsigned short s) {
    unsigned u = (unsigned)s << 16;
    float f;
    memcpy(&f, &u, 4);
    return f;
}
__device__ inline short8v as_s8(uint4 u) {
    union { uint4 a; short8v b; } c;
    c.a = u;
    return c.b;
}

// ---------------------------------------------------------------------------
// Prepack: Wy[1024][32] f32 -> fragment-ready packed bf16 hi/lo in d_ws.
// Entry e = ks*256 + tf*128 + h*64 + lane ; 16 B each; 8192 entries = 128 KB.
// Element p: bf16x2( Wy[ks*32+(lane>>4)*8+2p][f], ...[2p+1][f] ),
// f=(lane&15)+tf*16; h=0 hi, h=1 lo. Same (group,elem)->j map as the
// x-fragment loader => contraction correct for ANY internal HW k-order.
// ---------------------------------------------------------------------------
__global__ __launch_bounds__(128)
void ge_prepack(const float* __restrict__ Wy, uint4* __restrict__ wyp)
{
    const int e  = blockIdx.x * 128 + threadIdx.x;   // 0..8191
    const int l  = e & 63;
    const int h  = (e >> 6) & 1;
    const int tf = (e >> 7) & 1;
    const int ks = e >> 8;
    const int f  = (l & 15) + tf * 16;
    const int j0 = ks * 32 + (l >> 4) * 8;

    unsigned d[4];
#pragma unroll
    for (int p = 0; p < 4; ++p) {
        const float v0 = Wy[(size_t)(j0 + 2 * p) * kF + f];
        const float v1 = Wy[(size_t)(j0 + 2 * p + 1) * kF + f];
        unsigned short s0, s1;
        if (h == 0) {
            s0 = bf16_hi_bits(v0);
            s1 = bf16_hi_bits(v1);
        } else {
            s0 = bf16_hi_bits(v0 - bf16_bits_to_f(bf16_hi_bits(v0)));
            s1 = bf16_hi_bits(v1 - bf16_bits_to_f(bf16_hi_bits(v1)));
        }
        d[p] = (unsigned)s0 | ((unsigned)s1 << 16);
    }
    wyp[e] = make_uint4(d[0], d[1], d[2], d[3]);
}

// ---------------------------------------------------------------------------
// Stage 1 (MFMA, LDS-staged x AND B):
//   t[row,f] = (sum_j x[row,j]*Wy[j,f]) * Wx[row%I,f]
// B amortization: staging the 4-K-step B chunk (16 KB) per BLOCK cuts B
// global traffic 256 MB -> 64 MB (4 waves share).
// ROUND-14 BUG: launch_bounds(256,3) cap (~170) < peak pressure -> compiler
// demoted sregX/sregB to scratch (WRITE_SIZE 160 MB = 1.2 KB/thread = the
// staging regs x 8 tiles). SESSION LAW (5th occurrence): register-staged
// structures need the full 256 cap -> launch_bounds(256,2). LDS 49.8 KB
// still allows 3 blocks/CU if the allocator lands <=128 VGPR.
// T14 pipeline: next tile's global loads issue BEFORE compute, LDS writes
// after a barrier pair (2 barriers/tile, 8 tiles of 4 K-steps).
// A-frag LDS reads: stride-132 rows -> bank-group (mrow+2g)%8, optimal.
// B-frag LDS reads: 64 consecutive quads -> conflict-free.
// bf16-split: x*w ~= xh*wh + xh*wl + xl*wh (xl*wl dropped, ~2^-18 rel).
// D layout (verified m89): n=lane&15, m=(lane>>4)*4+reg.
// ---------------------------------------------------------------------------
__global__ __launch_bounds__(256, 2)
void ge_stage1_mfma(const float* __restrict__ x,
                    const float* __restrict__ Wx,
                    const uint4* __restrict__ wyp,
                    float* __restrict__ t)
{
    __shared__ float xb[64 * 132];       // 33.8 KB, row stride 132
    __shared__ uint4 bb[1024];           // 16 KB, 4 K-steps of fragments

    const int tid  = threadIdx.x;
    const int lane = tid & 63;
    const int wv   = tid >> 6;           // wave 0..3 = m-tile (16 rows)
    const int mrow = lane & 15;
    const int g    = lane >> 4;
    const int rowBase = blockIdx.x * 64;

    // staging coords (x): thread covers col sc, rows sr0 + p*8
    const int sr0 = tid >> 5;            // 0..7
    const int sc  = (tid & 31) * 4;      // float col 0..124

    const int lbase = (wv * 16 + mrow) * 132 + g * 8;

    f32x4 c0 = {0.f, 0.f, 0.f, 0.f};
    f32x4 c1 = {0.f, 0.f, 0.f, 0.f};
    float4 sregX[8];
    uint4  sregB[4];

#define SLOAD(ti)                                                       \
    {                                                                   \
        _Pragma("unroll")                                               \
        for (int p = 0; p < 8; ++p)                                     \
            sregX[p] = *reinterpret_cast<const float4*>(                \
                x + (size_t)(rowBase + sr0 + p * 8) * kJ                \
                  + (ti) * 128 + sc);                                   \
        _Pragma("unroll")                                               \
        for (int q = 0; q < 4; ++q)                                     \
            sregB[q] = wyp[(ti) * 1024 + tid + q * 256];                \
    }

#define SWRITE()                                                        \
    {                                                                   \
        _Pragma("unroll")                                               \
        for (int p = 0; p < 8; ++p)                                     \
            *reinterpret_cast<float4*>(                                 \
                &xb[(sr0 + p * 8) * 132 + sc]) = sregX[p];              \
        _Pragma("unroll")                                               \
        for (int q = 0; q < 4; ++q)                                     \
            bb[tid + q * 256] = sregB[q];                               \
    }

    SLOAD(0)
    SWRITE()
    __syncthreads();

#pragma unroll
    for (int ti = 0; ti < 8; ++ti) {
        if (ti < 7) { SLOAD(ti + 1) }           // issue early (T14)

#pragma unroll
        for (int kk = 0; kk < 4; ++kk) {        // K-steps within tile
            const uint4 b0h = bb[kk * 256 + lane];
            const uint4 b0l = bb[kk * 256 + 64 + lane];
            const uint4 b1h = bb[kk * 256 + 128 + lane];
            const uint4 b1l = bb[kk * 256 + 192 + lane];

            const float4 xa = *reinterpret_cast<const float4*>(
                &xb[lbase + kk * 32]);
            const float4 xc = *reinterpret_cast<const float4*>(
                &xb[lbase + kk * 32 + 4]);
            const float xv[8] = {xa.x, xa.y, xa.z, xa.w,
                                 xc.x, xc.y, xc.z, xc.w};

            short8v ah, al;
#pragma unroll
            for (int e = 0; e < 8; ++e) {
                const unsigned short hb = bf16_hi_bits(xv[e]);
                const float hf = bf16_bits_to_f(hb);
                const unsigned short lb = bf16_hi_bits(xv[e] - hf);
                ah[e] = (short)hb;
                al[e] = (short)lb;
            }

            c0 = __builtin_amdgcn_mfma_f32_16x16x32_bf16(ah, as_s8(b0h), c0, 0, 0, 0);
            c1 = __builtin_amdgcn_mfma_f32_16x16x32_bf16(ah, as_s8(b1h), c1, 0, 0, 0);
            c0 = __builtin_amdgcn_mfma_f32_16x16x32_bf16(ah, as_s8(b0l), c0, 0, 0, 0);
            c1 = __builtin_amdgcn_mfma_f32_16x16x32_bf16(ah, as_s8(b1l), c1, 0, 0, 0);
            c0 = __builtin_amdgcn_mfma_f32_16x16x32_bf16(al, as_s8(b0h), c0, 0, 0, 0);
            c1 = __builtin_amdgcn_mfma_f32_16x16x32_bf16(al, as_s8(b1h), c1, 0, 0, 0);
        }

        if (ti < 7) {
            __syncthreads();                    // all waves done reading LDS
            SWRITE()                            // vmcnt wait lands here
            __syncthreads();                    // new tile visible
        }
    }

    // epilogue: gate by Wx, store. D: n=lane&15, m=(lane>>4)*4+reg.
    const int n = lane & 15;
#pragma unroll
    for (int r = 0; r < 4; ++r) {
        const int row = rowBase + wv * 16 + g * 4 + r;
        const int i   = row & (kI - 1);
        t[(size_t)row * kF + n]      = c0[r] * Wx[(size_t)i * kF + n];
        t[(size_t)row * kF + 16 + n] = c1[r] * Wx[(size_t)i * kF + 16 + n];
    }
#undef SLOAD
#undef SWRITE
}

// ---------------------------------------------------------------------------
// Stage 1 (VALU fallback, ~83 us): used if ws lacks wyp room.
// ---------------------------------------------------------------------------
constexpr int kCJ = 256;

#define LOADW(buf, jabs)                                               \
    _Pragma("unroll")                                                  \
    for (int r = 0; r < 8; ++r)                                        \
        buf[r] = *reinterpret_cast<const float4*>(                     \
            xrow0 + (size_t)r * kJ + (jabs));

#define COMPW(buf, jl)                                                 \
    _Pragma("unroll")                                                  \
    for (int u = 0; u < 4; ++u) {                                      \
        const float4 wv = *reinterpret_cast<const float4*>(            \
            &wyb[(((jl) + jo * 4 + u) * 8 + fq) * 4]);                 \
        _Pragma("unroll")                                              \
        for (int r = 0; r < 8; ++r) {                                  \
            const float xs = (u == 0) ? buf[r].x : (u == 1) ? buf[r].y \
                           : (u == 2) ? buf[r].z : buf[r].w;           \
            acc[r].x = fmaf(xs, wv.x, acc[r].x);                       \
            acc[r].y = fmaf(xs, wv.y, acc[r].y);                       \
            acc[r].z = fmaf(xs, wv.z, acc[r].z);                       \
            acc[r].w = fmaf(xs, wv.w, acc[r].w);                       \
        }                                                              \
    }

#define STEP(bc, bp, gw, wd)                                           \
    if ((gw) + 2 < 32) { LOADW(bp, ((gw) + 2) * 32) }                  \
    COMPW(bc, (wd) * 32)

__global__ __launch_bounds__(256, 2)
void ge_stage1_valu(const float* __restrict__ x,
                    const float* __restrict__ Wx,
                    const float* __restrict__ Wy,
                    float* __restrict__ t)
{
    __shared__ float wyb[kCJ * kF];

    const int tid  = threadIdx.x;
    const int lane = tid & 63;
    const int w    = tid >> 6;
    const int fq   = lane & 7;
    const int jo   = lane >> 3;
    const int rowBase = blockIdx.x * 32 + w * 8;

    const float* __restrict__ xrow0 = x + (size_t)rowBase * kJ + jo * 4;

    float4 acc[8];
#pragma unroll
    for (int r = 0; r < 8; ++r) acc[r] = make_float4(0.f, 0.f, 0.f, 0.f);

    float4 x0[8], x1[8], x2[8];
    LOADW(x0, 0)
    LOADW(x1, 32)

#pragma unroll
    for (int c = 0; c < 4; ++c) {
        __syncthreads();
        {
            const float4* src = reinterpret_cast<const float4*>(
                Wy + (size_t)c * kCJ * kF);
            float4* dst = reinterpret_cast<float4*>(wyb);
#pragma unroll
            for (int p = 0; p < 8; ++p)
                dst[tid + p * 256] = src[tid + p * 256];
        }
        __syncthreads();

#pragma unroll
        for (int wd = 0; wd < 8; ++wd) {
            const int gw = c * 8 + wd;
            const int ph = gw % 3;
            if (ph == 0)      { STEP(x0, x2, gw, wd) }
            else if (ph == 1) { STEP(x1, x0, gw, wd) }
            else              { STEP(x2, x1, gw, wd) }
        }
    }

    float4 ov = make_float4(0.f, 0.f, 0.f, 0.f);
#pragma unroll
    for (int r = 0; r < 8; ++r) {
        float4 v = acc[r];
        v.x += __shfl_xor(v.x, 8);  v.y += __shfl_xor(v.y, 8);
        v.z += __shfl_xor(v.z, 8);  v.w += __shfl_xor(v.w, 8);
        v.x += __shfl_xor(v.x, 16); v.y += __shfl_xor(v.y, 16);
        v.z += __shfl_xor(v.z, 16); v.w += __shfl_xor(v.w, 16);
        v.x += __shfl_xor(v.x, 32); v.y += __shfl_xor(v.y, 32);
        v.z += __shfl_xor(v.z, 32); v.w += __shfl_xor(v.w, 32);
        if (jo == r) ov = v;
    }

    const int f0  = fq * 4;
    const int row = rowBase + jo;
    const int i   = row & (kI - 1);
    const float4 g = *reinterpret_cast<const float4*>(Wx + (size_t)i * kF + f0);
    ov.x *= g.x; ov.y *= g.y; ov.z *= g.z; ov.w *= g.w;
    *reinterpret_cast<float4*>(t + (size_t)row * kF + f0) = ov;
}

// ---------------------------------------------------------------------------
// Stage 2: out[row,k] = sum_f t[row,f] * Wz[k,f]   (~28 us measured, round 5)
// ---------------------------------------------------------------------------
__global__ __launch_bounds__(512, 2)
void ge_stage2(const float* __restrict__ t,
               const float* __restrict__ Wz,
               float* __restrict__ out)
{
    __shared__ float t2[64][kF];

    const int tid = threadIdx.x;
    const int rowBase = blockIdx.x * 64;

    reinterpret_cast<float4*>(&t2[0][0])[tid] =
        reinterpret_cast<const float4*>(t + (size_t)rowBase * kF)[tid];

    const int k0 = tid * 2;
    float4 wa[8], wb[8];
#pragma unroll
    for (int q = 0; q < 8; ++q) {
        wa[q] = *reinterpret_cast<const float4*>(Wz + (size_t)k0 * kF + q * 4);
        wb[q] = *reinterpret_cast<const float4*>(Wz + (size_t)(k0 + 1) * kF + q * 4);
    }
    __syncthreads();

    float* __restrict__ orow = out + (size_t)rowBase * kK + k0;

    for (int r = 0; r < 64; ++r) {
        float4 tr[8];
#pragma unroll
        for (int q = 0; q < 8; ++q)
            tr[q] = *reinterpret_cast<const float4*>(&t2[r][q * 4]);

        float a0 = 0.f, a1 = 0.f, b0 = 0.f, b1 = 0.f;
#pragma unroll
        for (int q = 0; q < 8; q += 2) {
            a0 = fmaf(tr[q].x, wa[q].x, a0);
            a0 = fmaf(tr[q].y, wa[q].y, a0);
            a0 = fmaf(tr[q].z, wa[q].z, a0);
            a0 = fmaf(tr[q].w, wa[q].w, a0);
            a1 = fmaf(tr[q + 1].x, wa[q + 1].x, a1);
            a1 = fmaf(tr[q + 1].y, wa[q + 1].y, a1);
            a1 = fmaf(tr[q + 1].z, wa[q + 1].z, a1);
            a1 = fmaf(tr[q + 1].w, wa[q + 1].w, a1);
            b0 = fmaf(tr[q].x, wb[q].x, b0);
            b0 = fmaf(tr[q].y, wb[q].y, b0);
            b0 = fmaf(tr[q].z, wb[q].z, b0);
            b0 = fmaf(tr[q].w, wb[q].w, b0);
            b1 = fmaf(tr[q + 1].x, wb[q + 1].x, b1);
            b1 = fmaf(tr[q + 1].y, wb[q + 1].y, b1);
            b1 = fmaf(tr[q + 1].z, wb[q + 1].z, b1);
            b1 = fmaf(tr[q + 1].w, wb[q + 1].w, b1);
        }
        float2 o;
        o.x = a0 + a1;
        o.y = b0 + b1;
        *reinterpret_cast<float2*>(orow + (size_t)r * kK) = o;
    }
}

// ---------------------------------------------------------------------------
// Fallback: round-1 fused kernel (proven correct) if ws too small.
// ---------------------------------------------------------------------------
__global__ __launch_bounds__(256, 2)
void gated_encoder_fused(const float* __restrict__ x,
                         const float* __restrict__ Wx,
                         const float* __restrict__ Wy,
                         const float* __restrict__ Wz,
                         float* __restrict__ out)
{
    __shared__ float t2[64][kF + 4];

    const int tid  = threadIdx.x;
    const int lane = tid & 63;
    const int wv   = tid >> 6;

    const int rloc = wv * 16 + (lane >> 2);
    const int row  = blockIdx.x * 64 + rloc;
    const int fg8  = (lane & 3) * 8;

    const float* __restrict__ xrow = x + (size_t)row * kJ;

    float acc[8];
#pragma unroll
    for (int u = 0; u < 8; ++u) acc[u] = 0.0f;

    for (int j = 0; j < kJ; j += 8) {
        const float4 xv0 = *reinterpret_cast<const float4*>(xrow + j);
        const float4 xv1 = *reinterpret_cast<const float4*>(xrow + j + 4);
        const float xs[8] = {xv0.x, xv0.y, xv0.z, xv0.w,
                             xv1.x, xv1.y, xv1.z, xv1.w};
#pragma unroll
        for (int u = 0; u < 8; ++u) {
            const float* wyp = Wy + (size_t)(j + u) * kF + fg8;
            const float4 w0 = *reinterpret_cast<const float4*>(wyp);
            const float4 w1 = *reinterpret_cast<const float4*>(wyp + 4);
            acc[0] = fmaf(xs[u], w0.x, acc[0]);
            acc[1] = fmaf(xs[u], w0.y, acc[1]);
            acc[2] = fmaf(xs[u], w0.z, acc[2]);
            acc[3] = fmaf(xs[u], w0.w, acc[3]);
            acc[4] = fmaf(xs[u], w1.x, acc[4]);
            acc[5] = fmaf(xs[u], w1.y, acc[5]);
            acc[6] = fmaf(xs[u], w1.z, acc[6]);
            acc[7] = fmaf(xs[u], w1.w, acc[7]);
        }
    }

    const int i = row & (kI - 1);
    const float* wxp = Wx + (size_t)i * kF + fg8;
    const float4 g0 = *reinterpret_cast<const float4*>(wxp);
    const float4 g1 = *reinterpret_cast<const float4*>(wxp + 4);
    float4 r0, r1;
    r0.x = acc[0] * g0.x;  r0.y = acc[1] * g0.y;
    r0.z = acc[2] * g0.z;  r0.w = acc[3] * g0.w;
    r1.x = acc[4] * g1.x;  r1.y = acc[5] * g1.y;
    r1.z = acc[6] * g1.z;  r1.w = acc[7] * g1.w;
    *reinterpret_cast<float4*>(&t2[rloc][fg8])     = r0;
    *reinterpret_cast<float4*>(&t2[rloc][fg8 + 4]) = r1;

    __syncthreads();

    const size_t outBase = (size_t)blockIdx.x * 64 * kK;

#pragma unroll
    for (int pass = 0; pass < 2; ++pass) {
        const int k1 = pass * 512 + tid;
        const int k2 = k1 + 256;
        const float* wz1 = Wz + (size_t)k1 * kF;
        const float* wz2 = Wz + (size_t)k2 * kF;
        float4 z1[8], z2[8];
#pragma unroll
        for (int m = 0; m < 8; ++m) {
            z1[m] = *reinterpret_cast<const float4*>(wz1 + 4 * m);
            z2[m] = *reinterpret_cast<const float4*>(wz2 + 4 * m);
        }
        for (int r = 0; r < 64; ++r) {
            float4 a1 = {0.f, 0.f, 0.f, 0.f};
            float4 a2 = {0.f, 0.f, 0.f, 0.f};
#pragma unroll
            for (int m = 0; m < 8; ++m) {
                const float4 tv = *reinterpret_cast<const float4*>(&t2[r][4 * m]);
                a1.x = fmaf(tv.x, z1[m].x, a1.x);
                a1.y = fmaf(tv.y, z1[m].y, a1.y);
                a1.z = fmaf(tv.z, z1[m].z, a1.z);
                a1.w = fmaf(tv.w, z1[m].w, a1.w);
                a2.x = fmaf(tv.x, z2[m].x, a2.x);
                a2.y = fmaf(tv.y, z2[m].y, a2.y);
                a2.z = fmaf(tv.z, z2[m].z, a2.z);
                a2.w = fmaf(tv.w, z2[m].w, a2.w);
            }
            out[outBase + (size_t)r * kK + k1] = (a1.x + a1.y) + (a1.z + a1.w);
            out[outBase + (size_t)r * kK + k2] = (a2.x + a2.y) + (a2.z + a2.w);
        }
    }
}

extern "C" void kernel_launch(void* const* d_in, const int* in_sizes, int n_in,
                              void* d_out, int out_size, void* d_ws, size_t ws_size,
                              hipStream_t stream) {
    const float* x  = (const float*)d_in[0];   // (B, I, J)
    const float* Wx = (const float*)d_in[1];   // (I, F)
    const float* Wy = (const float*)d_in[2];   // (J, F)
    const float* Wz = (const float*)d_in[3];   // (K, F)
    float* out = (float*)d_out;                // (B, I, K) f32

    const size_t tBytes  = (size_t)kRows * kF * sizeof(float);   // 4 MiB
    const size_t wyBytes = 8192 * sizeof(uint4);                 // 128 KiB

    if (ws_size >= tBytes + wyBytes && d_ws != nullptr) {
        float* t   = (float*)d_ws;
        uint4* wyp = (uint4*)((char*)d_ws + tBytes);
        ge_prepack<<<dim3(64), 128, 0, stream>>>(Wy, wyp);
        ge_stage1_mfma<<<dim3(kRows / 64), 256, 0, stream>>>(x, Wx, wyp, t);
        ge_stage2<<<dim3(kRows / 64), 512, 0, stream>>>(t, Wz, out);
    } else if (ws_size >= tBytes && d_ws != nullptr) {
        float* t = (float*)d_ws;
        ge_stage1_valu<<<dim3(kRows / 32), 256, 0, stream>>>(x, Wx, Wy, t);
        ge_stage2<<<dim3(kRows / 64), 512, 0, stream>>>(t, Wz, out);
    } else {
        gated_encoder_fused<<<dim3(kRows / 64), 256, 0, stream>>>(x, Wx, Wy, Wz, out);
    }
}

// Round 16
// 87.147 us; speedup vs baseline: 1.5568x; 1.5568x over previous
//
#include <hip/hip_runtime.h>
#include <hip/hip_bf16.h>
#include <string.h>

// GatedEncoderLayer: B=16, I=2048, J=1024, K=1024, F=32
// out[row,k] = sum_f [ (sum_j x[row,j]*Wy[j,f]) * Wx[row%I,f] ] * Wz[k,f]
constexpr int kI = 2048;
constexpr int kJ = 1024;
constexpr int kK = 1024;
constexpr int kF = 32;
constexpr int kRows = 16 * 2048;        // 32768

typedef __attribute__((ext_vector_type(8))) short short8v;
typedef __attribute__((ext_vector_type(4))) float f32x4;

__device__ inline unsigned short bf16_hi_bits(float v) {
    __hip_bfloat16 h = __float2bfloat16(v);      // RNE on gfx950
    unsigned short s;
    memcpy(&s, &h, 2);
    return s;
}
__device__ inline float bf16_bits_to_f(unsigned short s) {
    unsigned u = (unsigned)s << 16;
    float f;
    memcpy(&f, &u, 4);
    return f;
}
__device__ inline short8v as_s8(uint4 u) {
    union { uint4 a; short8v b; } c;
    c.a = u;
    return c.b;
}
// async global->LDS, 16B per lane; LDS dest = wave-uniform base + lane*16
__device__ inline void gl_lds16(const void* g, void* l) {
    __builtin_amdgcn_global_load_lds(
        (const __attribute__((address_space(1))) void*)g,
        (__attribute__((address_space(3))) void*)l,
        16, 0, 0);
}

// ---------------------------------------------------------------------------
// Prepack: Wy[1024][32] f32 -> fragment-ready packed bf16 hi/lo in d_ws.
// Entry e = ks*256 + tf*128 + h*64 + lane ; 16 B each; 8192 entries = 128 KB.
// Element p: bf16x2( Wy[ks*32+(lane>>4)*8+2p][f], ...[2p+1][f] ),
// f=(lane&15)+tf*16; h=0 hi, h=1 lo. Same (group,elem)->j map as the
// x-fragment loader => contraction correct for ANY internal HW k-order.
// ---------------------------------------------------------------------------
__global__ __launch_bounds__(128)
void ge_prepack(const float* __restrict__ Wy, uint4* __restrict__ wyp)
{
    const int e  = blockIdx.x * 128 + threadIdx.x;   // 0..8191
    const int l  = e & 63;
    const int h  = (e >> 6) & 1;
    const int tf = (e >> 7) & 1;
    const int ks = e >> 8;
    const int f  = (l & 15) + tf * 16;
    const int j0 = ks * 32 + (l >> 4) * 8;

    unsigned d[4];
#pragma unroll
    for (int p = 0; p < 4; ++p) {
        const float v0 = Wy[(size_t)(j0 + 2 * p) * kF + f];
        const float v1 = Wy[(size_t)(j0 + 2 * p + 1) * kF + f];
        unsigned short s0, s1;
        if (h == 0) {
            s0 = bf16_hi_bits(v0);
            s1 = bf16_hi_bits(v1);
        } else {
            s0 = bf16_hi_bits(v0 - bf16_bits_to_f(bf16_hi_bits(v0)));
            s1 = bf16_hi_bits(v1 - bf16_bits_to_f(bf16_hi_bits(v1)));
        }
        d[p] = (unsigned)s0 | ((unsigned)s1 << 16);
    }
    wyp[e] = make_uint4(d[0], d[1], d[2], d[3]);
}

// ---------------------------------------------------------------------------
// Stage 1 (MFMA, global_load_lds staging — NO staging registers):
//   t[row,f] = (sum_j x[row,j]*Wy[j,f]) * Wx[row%I,f]
// Rounds 13-15 post-mortem: global->reg->LDS staging arrays are demoted to
// scratch by the compiler REGARDLESS of launch_bounds (r14 (256,3) and r15
// (256,2) bit-identical: VGPR=68, WRITE 160MB). Fix: async DMA staging via
// __builtin_amdgcn_global_load_lds (16B/lane) — zero staging regs.
// Double-buffered: {x 64rows x 64j = 16KB} + {B 2-K-steps = 8KB} per buf,
// 48KB LDS. Per tile each wave issues 4 x-loads + 2 B-loads (wave-uniform
// LDS base + lane*16), then computes 2 K-steps from the other buffer; ONE
// barrier/tile (its vmcnt(0) drain guarantees tile-ready; m97 pattern).
// x slots source-XOR-swizzled (col16 ^ (row&7), rule #21: linear LDS dest +
// swizzled GLOBAL src + swizzled ds_read) -> 8-phase-optimal A reads
// (unswizzled would be 16-phase: bank = fc%32 depends only on g).
// B reads lane-consecutive -> optimal.
// bf16-split: x*w ~= xh*wh + xh*wl + xl*wh (xl*wl dropped, ~2^-18 rel).
// D layout (verified m89 + rounds 11-15 passing): n=lane&15, m=(lane>>4)*4+reg.
// ---------------------------------------------------------------------------
__global__ __launch_bounds__(256, 2)
void ge_stage1_mfma(const float* __restrict__ x,
                    const float* __restrict__ Wx,
                    const uint4* __restrict__ wyp,
                    float* __restrict__ t)
{
    __shared__ float4 xb4[2][1024];      // 2 x 16 KB: 64 rows x 16 slots
    __shared__ uint4  bb4[2][512];       // 2 x 8 KB: 2 K-steps x 256 frags

    const int tid  = threadIdx.x;
    const int lane = tid & 63;
    const int wv   = tid >> 6;           // wave 0..3 = m-tile (16 rows)
    const int mrow = lane & 15;
    const int g    = lane >> 4;
    const int rowBase = blockIdx.x * 64;

    f32x4 c0 = {0.f, 0.f, 0.f, 0.f};
    f32x4 c1 = {0.f, 0.f, 0.f, 0.f};

    // per-lane staging source coords (x): 4 instrs, lane -> (row, slot)
    // instr q: row = wv*16 + q*4 + (lane>>4), slot c = lane&15;
    // source col16 = c ^ (row&7)  (so LDS slot c holds swizzled data)
#define STAGE(buf, ti)                                                  \
    {                                                                   \
        _Pragma("unroll")                                               \
        for (int q = 0; q < 4; ++q) {                                   \
            const int srow = wv * 16 + q * 4 + (lane >> 4);             \
            const int sc   = lane & 15;                                 \
            gl_lds16(x + (size_t)(rowBase + srow) * kJ + (ti) * 64      \
                       + 4 * (sc ^ (srow & 7)),                         \
                     &xb4[buf][(wv * 16 + q * 4) * 16]);                \
        }                                                               \
        _Pragma("unroll")                                               \
        for (int q = 0; q < 2; ++q)                                     \
            gl_lds16(wyp + (size_t)(ti) * 512 + wv * 128 + q * 64 + lane, \
                     &bb4[buf][wv * 128 + q * 64]);                     \
    }

    STAGE(0, 0)
    __syncthreads();                     // vmcnt(0) drain -> tile 0 ready

#pragma unroll
    for (int ti = 0; ti < 16; ++ti) {
        const int cb = ti & 1;
        if (ti < 15) { STAGE((ti + 1) & 1, ti + 1) }   // async prefetch

#pragma unroll
        for (int kk2 = 0; kk2 < 2; ++kk2) {            // K-steps in tile
            const uint4 b0h = bb4[cb][kk2 * 256 + lane];
            const uint4 b0l = bb4[cb][kk2 * 256 + 64 + lane];
            const uint4 b1h = bb4[cb][kk2 * 256 + 128 + lane];
            const uint4 b1l = bb4[cb][kk2 * 256 + 192 + lane];

            const int s0 = (kk2 * 8 + g * 2) ^ (mrow & 7);
            const int s1 = (kk2 * 8 + g * 2 + 1) ^ (mrow & 7);
            const float4 xa = xb4[cb][(wv * 16 + mrow) * 16 + s0];
            const float4 xc = xb4[cb][(wv * 16 + mrow) * 16 + s1];
            const float xv[8] = {xa.x, xa.y, xa.z, xa.w,
                                 xc.x, xc.y, xc.z, xc.w};

            short8v ah, al;
#pragma unroll
            for (int e = 0; e < 8; ++e) {
                const unsigned short hb = bf16_hi_bits(xv[e]);
                const float hf = bf16_bits_to_f(hb);
                const unsigned short lb = bf16_hi_bits(xv[e] - hf);
                ah[e] = (short)hb;
                al[e] = (short)lb;
            }

            c0 = __builtin_amdgcn_mfma_f32_16x16x32_bf16(ah, as_s8(b0h), c0, 0, 0, 0);
            c1 = __builtin_amdgcn_mfma_f32_16x16x32_bf16(ah, as_s8(b1h), c1, 0, 0, 0);
            c0 = __builtin_amdgcn_mfma_f32_16x16x32_bf16(ah, as_s8(b0l), c0, 0, 0, 0);
            c1 = __builtin_amdgcn_mfma_f32_16x16x32_bf16(ah, as_s8(b1l), c1, 0, 0, 0);
            c0 = __builtin_amdgcn_mfma_f32_16x16x32_bf16(al, as_s8(b0h), c0, 0, 0, 0);
            c1 = __builtin_amdgcn_mfma_f32_16x16x32_bf16(al, as_s8(b1h), c1, 0, 0, 0);
        }

        __syncthreads();   // vmcnt(0) drain: next tile ready; reads of cb done
    }

    // epilogue: gate by Wx, store. D: n=lane&15, m=(lane>>4)*4+reg.
    const int n = lane & 15;
#pragma unroll
    for (int r = 0; r < 4; ++r) {
        const int row = rowBase + wv * 16 + g * 4 + r;
        const int i   = row & (kI - 1);
        t[(size_t)row * kF + n]      = c0[r] * Wx[(size_t)i * kF + n];
        t[(size_t)row * kF + 16 + n] = c1[r] * Wx[(size_t)i * kF + 16 + n];
    }
#undef STAGE
}

// ---------------------------------------------------------------------------
// Stage 1 (VALU fallback, ~83 us): used if ws lacks wyp room.
// ---------------------------------------------------------------------------
constexpr int kCJ = 256;

#define LOADW(buf, jabs)                                               \
    _Pragma("unroll")                                                  \
    for (int r = 0; r < 8; ++r)                                        \
        buf[r] = *reinterpret_cast<const float4*>(                     \
            xrow0 + (size_t)r * kJ + (jabs));

#define COMPW(buf, jl)                                                 \
    _Pragma("unroll")                                                  \
    for (int u = 0; u < 4; ++u) {                                      \
        const float4 wv = *reinterpret_cast<const float4*>(            \
            &wyb[(((jl) + jo * 4 + u) * 8 + fq) * 4]);                 \
        _Pragma("unroll")                                              \
        for (int r = 0; r < 8; ++r) {                                  \
            const float xs = (u == 0) ? buf[r].x : (u == 1) ? buf[r].y \
                           : (u == 2) ? buf[r].z : buf[r].w;           \
            acc[r].x = fmaf(xs, wv.x, acc[r].x);                       \
            acc[r].y = fmaf(xs, wv.y, acc[r].y);                       \
            acc[r].z = fmaf(xs, wv.z, acc[r].z);                       \
            acc[r].w = fmaf(xs, wv.w, acc[r].w);                       \
        }                                                              \
    }

#define STEP(bc, bp, gw, wd)                                           \
    if ((gw) + 2 < 32) { LOADW(bp, ((gw) + 2) * 32) }                  \
    COMPW(bc, (wd) * 32)

__global__ __launch_bounds__(256, 2)
void ge_stage1_valu(const float* __restrict__ x,
                    const float* __restrict__ Wx,
                    const float* __restrict__ Wy,
                    float* __restrict__ t)
{
    __shared__ float wyb[kCJ * kF];

    const int tid  = threadIdx.x;
    const int lane = tid & 63;
    const int w    = tid >> 6;
    const int fq   = lane & 7;
    const int jo   = lane >> 3;
    const int rowBase = blockIdx.x * 32 + w * 8;

    const float* __restrict__ xrow0 = x + (size_t)rowBase * kJ + jo * 4;

    float4 acc[8];
#pragma unroll
    for (int r = 0; r < 8; ++r) acc[r] = make_float4(0.f, 0.f, 0.f, 0.f);

    float4 x0[8], x1[8], x2[8];
    LOADW(x0, 0)
    LOADW(x1, 32)

#pragma unroll
    for (int c = 0; c < 4; ++c) {
        __syncthreads();
        {
            const float4* src = reinterpret_cast<const float4*>(
                Wy + (size_t)c * kCJ * kF);
            float4* dst = reinterpret_cast<float4*>(wyb);
#pragma unroll
            for (int p = 0; p < 8; ++p)
                dst[tid + p * 256] = src[tid + p * 256];
        }
        __syncthreads();

#pragma unroll
        for (int wd = 0; wd < 8; ++wd) {
            const int gw = c * 8 + wd;
            const int ph = gw % 3;
            if (ph == 0)      { STEP(x0, x2, gw, wd) }
            else if (ph == 1) { STEP(x1, x0, gw, wd) }
            else              { STEP(x2, x1, gw, wd) }
        }
    }

    float4 ov = make_float4(0.f, 0.f, 0.f, 0.f);
#pragma unroll
    for (int r = 0; r < 8; ++r) {
        float4 v = acc[r];
        v.x += __shfl_xor(v.x, 8);  v.y += __shfl_xor(v.y, 8);
        v.z += __shfl_xor(v.z, 8);  v.w += __shfl_xor(v.w, 8);
        v.x += __shfl_xor(v.x, 16); v.y += __shfl_xor(v.y, 16);
        v.z += __shfl_xor(v.z, 16); v.w += __shfl_xor(v.w, 16);
        v.x += __shfl_xor(v.x, 32); v.y += __shfl_xor(v.y, 32);
        v.z += __shfl_xor(v.z, 32); v.w += __shfl_xor(v.w, 32);
        if (jo == r) ov = v;
    }

    const int f0  = fq * 4;
    const int row = rowBase + jo;
    const int i   = row & (kI - 1);
    const float4 g = *reinterpret_cast<const float4*>(Wx + (size_t)i * kF + f0);
    ov.x *= g.x; ov.y *= g.y; ov.z *= g.z; ov.w *= g.w;
    *reinterpret_cast<float4*>(t + (size_t)row * kF + f0) = ov;
}

// ---------------------------------------------------------------------------
// Stage 2: out[row,k] = sum_f t[row,f] * Wz[k,f]   (~28 us measured, round 5)
// ---------------------------------------------------------------------------
__global__ __launch_bounds__(512, 2)
void ge_stage2(const float* __restrict__ t,
               const float* __restrict__ Wz,
               float* __restrict__ out)
{
    __shared__ float t2[64][kF];

    const int tid = threadIdx.x;
    const int rowBase = blockIdx.x * 64;

    reinterpret_cast<float4*>(&t2[0][0])[tid] =
        reinterpret_cast<const float4*>(t + (size_t)rowBase * kF)[tid];

    const int k0 = tid * 2;
    float4 wa[8], wb[8];
#pragma unroll
    for (int q = 0; q < 8; ++q) {
        wa[q] = *reinterpret_cast<const float4*>(Wz + (size_t)k0 * kF + q * 4);
        wb[q] = *reinterpret_cast<const float4*>(Wz + (size_t)(k0 + 1) * kF + q * 4);
    }
    __syncthreads();

    float* __restrict__ orow = out + (size_t)rowBase * kK + k0;

    for (int r = 0; r < 64; ++r) {
        float4 tr[8];
#pragma unroll
        for (int q = 0; q < 8; ++q)
            tr[q] = *reinterpret_cast<const float4*>(&t2[r][q * 4]);

        float a0 = 0.f, a1 = 0.f, b0 = 0.f, b1 = 0.f;
#pragma unroll
        for (int q = 0; q < 8; q += 2) {
            a0 = fmaf(tr[q].x, wa[q].x, a0);
            a0 = fmaf(tr[q].y, wa[q].y, a0);
            a0 = fmaf(tr[q].z, wa[q].z, a0);
            a0 = fmaf(tr[q].w, wa[q].w, a0);
            a1 = fmaf(tr[q + 1].x, wa[q + 1].x, a1);
            a1 = fmaf(tr[q + 1].y, wa[q + 1].y, a1);
            a1 = fmaf(tr[q + 1].z, wa[q + 1].z, a1);
            a1 = fmaf(tr[q + 1].w, wa[q + 1].w, a1);
            b0 = fmaf(tr[q].x, wb[q].x, b0);
            b0 = fmaf(tr[q].y, wb[q].y, b0);
            b0 = fmaf(tr[q].z, wb[q].z, b0);
            b0 = fmaf(tr[q].w, wb[q].w, b0);
            b1 = fmaf(tr[q + 1].x, wb[q + 1].x, b1);
            b1 = fmaf(tr[q + 1].y, wb[q + 1].y, b1);
            b1 = fmaf(tr[q + 1].z, wb[q + 1].z, b1);
            b1 = fmaf(tr[q + 1].w, wb[q + 1].w, b1);
        }
        float2 o;
        o.x = a0 + a1;
        o.y = b0 + b1;
        *reinterpret_cast<float2*>(orow + (size_t)r * kK) = o;
    }
}

// ---------------------------------------------------------------------------
// Fallback: round-1 fused kernel (proven correct) if ws too small.
// ---------------------------------------------------------------------------
__global__ __launch_bounds__(256, 2)
void gated_encoder_fused(const float* __restrict__ x,
                         const float* __restrict__ Wx,
                         const float* __restrict__ Wy,
                         const float* __restrict__ Wz,
                         float* __restrict__ out)
{
    __shared__ float t2[64][kF + 4];

    const int tid  = threadIdx.x;
    const int lane = tid & 63;
    const int wv   = tid >> 6;

    const int rloc = wv * 16 + (lane >> 2);
    const int row  = blockIdx.x * 64 + rloc;
    const int fg8  = (lane & 3) * 8;

    const float* __restrict__ xrow = x + (size_t)row * kJ;

    float acc[8];
#pragma unroll
    for (int u = 0; u < 8; ++u) acc[u] = 0.0f;

    for (int j = 0; j < kJ; j += 8) {
        const float4 xv0 = *reinterpret_cast<const float4*>(xrow + j);
        const float4 xv1 = *reinterpret_cast<const float4*>(xrow + j + 4);
        const float xs[8] = {xv0.x, xv0.y, xv0.z, xv0.w,
                             xv1.x, xv1.y, xv1.z, xv1.w};
#pragma unroll
        for (int u = 0; u < 8; ++u) {
            const float* wyp = Wy + (size_t)(j + u) * kF + fg8;
            const float4 w0 = *reinterpret_cast<const float4*>(wyp);
            const float4 w1 = *reinterpret_cast<const float4*>(wyp + 4);
            acc[0] = fmaf(xs[u], w0.x, acc[0]);
            acc[1] = fmaf(xs[u], w0.y, acc[1]);
            acc[2] = fmaf(xs[u], w0.z, acc[2]);
            acc[3] = fmaf(xs[u], w0.w, acc[3]);
            acc[4] = fmaf(xs[u], w1.x, acc[4]);
            acc[5] = fmaf(xs[u], w1.y, acc[5]);
            acc[6] = fmaf(xs[u], w1.z, acc[6]);
            acc[7] = fmaf(xs[u], w1.w, acc[7]);
        }
    }

    const int i = row & (kI - 1);
    const float* wxp = Wx + (size_t)i * kF + fg8;
    const float4 g0 = *reinterpret_cast<const float4*>(wxp);
    const float4 g1 = *reinterpret_cast<const float4*>(wxp + 4);
    float4 r0, r1;
    r0.x = acc[0] * g0.x;  r0.y = acc[1] * g0.y;
    r0.z = acc[2] * g0.z;  r0.w = acc[3] * g0.w;
    r1.x = acc[4] * g1.x;  r1.y = acc[5] * g1.y;
    r1.z = acc[6] * g1.z;  r1.w = acc[7] * g1.w;
    *reinterpret_cast<float4*>(&t2[rloc][fg8])     = r0;
    *reinterpret_cast<float4*>(&t2[rloc][fg8 + 4]) = r1;

    __syncthreads();

    const size_t outBase = (size_t)blockIdx.x * 64 * kK;

#pragma unroll
    for (int pass = 0; pass < 2; ++pass) {
        const int k1 = pass * 512 + tid;
        const int k2 = k1 + 256;
        const float* wz1 = Wz + (size_t)k1 * kF;
        const float* wz2 = Wz + (size_t)k2 * kF;
        float4 z1[8], z2[8];
#pragma unroll
        for (int m = 0; m < 8; ++m) {
            z1[m] = *reinterpret_cast<const float4*>(wz1 + 4 * m);
            z2[m] = *reinterpret_cast<const float4*>(wz2 + 4 * m);
        }
        for (int r = 0; r < 64; ++r) {
            float4 a1 = {0.f, 0.f, 0.f, 0.f};
            float4 a2 = {0.f, 0.f, 0.f, 0.f};
#pragma unroll
            for (int m = 0; m < 8; ++m) {
                const float4 tv = *reinterpret_cast<const float4*>(&t2[r][4 * m]);
                a1.x = fmaf(tv.x, z1[m].x, a1.x);
                a1.y = fmaf(tv.y, z1[m].y, a1.y);
                a1.z = fmaf(tv.z, z1[m].z, a1.z);
                a1.w = fmaf(tv.w, z1[m].w, a1.w);
                a2.x = fmaf(tv.x, z2[m].x, a2.x);
                a2.y = fmaf(tv.y, z2[m].y, a2.y);
                a2.z = fmaf(tv.z, z2[m].z, a2.z);
                a2.w = fmaf(tv.w, z2[m].w, a2.w);
            }
            out[outBase + (size_t)r * kK + k1] = (a1.x + a1.y) + (a1.z + a1.w);
            out[outBase + (size_t)r * kK + k2] = (a2.x + a2.y) + (a2.z + a2.w);
        }
    }
}

extern "C" void kernel_launch(void* const* d_in, const int* in_sizes, int n_in,
                              void* d_out, int out_size, void* d_ws, size_t ws_size,
                              hipStream_t stream) {
    const float* x  = (const float*)d_in[0];   // (B, I, J)
    const float* Wx = (const float*)d_in[1];   // (I, F)
    const float* Wy = (const float*)d_in[2];   // (J, F)
    const float* Wz = (const float*)d_in[3];   // (K, F)
    float* out = (float*)d_out;                // (B, I, K) f32

    const size_t tBytes  = (size_t)kRows * kF * sizeof(float);   // 4 MiB
    const size_t wyBytes = 8192 * sizeof(uint4);                 // 128 KiB

    if (ws_size >= tBytes + wyBytes && d_ws != nullptr) {
        float* t   = (float*)d_ws;
        uint4* wyp = (uint4*)((char*)d_ws + tBytes);
        ge_prepack<<<dim3(64), 128, 0, stream>>>(Wy, wyp);
        ge_stage1_mfma<<<dim3(kRows / 64), 256, 0, stream>>>(x, Wx, wyp, t);
        ge_stage2<<<dim3(kRows / 64), 512, 0, stream>>>(t, Wz, out);
    } else if (ws_size >= tBytes && d_ws != nullptr) {
        float* t = (float*)d_ws;
        ge_stage1_valu<<<dim3(kRows / 32), 256, 0, stream>>>(x, Wx, Wy, t);
        ge_stage2<<<dim3(kRows / 64), 512, 0, stream>>>(t, Wz, out);
    } else {
        gated_encoder_fused<<<dim3(kRows / 64), 256, 0, stream>>>(x, Wx, Wy, Wz, out);
    }
}

// Round 17
// 75.041 us; speedup vs baseline: 1.8080x; 1.1613x over previous
//
#include <hip/hip_runtime.h>
#include <hip/hip_bf16.h>
#include <string.h>

// GatedEncoderLayer: B=16, I=2048, J=1024, K=1024, F=32
// out[row,k] = sum_f [ (sum_j x[row,j]*Wy[j,f]) * Wx[row%I,f] ] * Wz[k,f]
constexpr int kI = 2048;
constexpr int kJ = 1024;
constexpr int kK = 1024;
constexpr int kF = 32;
constexpr int kRows = 16 * 2048;        // 32768

typedef __attribute__((ext_vector_type(8))) short short8v;
typedef __attribute__((ext_vector_type(4))) float f32x4;

__device__ inline unsigned short bf16_hi_bits(float v) {
    __hip_bfloat16 h = __float2bfloat16(v);      // RNE on gfx950
    unsigned short s;
    memcpy(&s, &h, 2);
    return s;
}
__device__ inline float bf16_bits_to_f(unsigned short s) {
    unsigned u = (unsigned)s << 16;
    float f;
    memcpy(&f, &u, 4);
    return f;
}
__device__ inline short8v as_s8(uint4 u) {
    union { uint4 a; short8v b; } c;
    c.a = u;
    return c.b;
}
// async global->LDS, 16B per lane; LDS dest = wave-uniform base + lane*16
__device__ inline void gl_lds16(const void* g, void* l) {
    __builtin_amdgcn_global_load_lds(
        (const __attribute__((address_space(1))) void*)g,
        (__attribute__((address_space(3))) void*)l,
        16, 0, 0);
}

// ---------------------------------------------------------------------------
// Prepack: Wy[1024][32] f32 -> fragment-ready packed bf16 hi/lo in d_ws.
// Entry e = ks*256 + tf*128 + h*64 + lane ; 16 B each; 8192 entries = 128 KB.
// Element p: bf16x2( Wy[ks*32+(lane>>4)*8+2p][f], ...[2p+1][f] ),
// f=(lane&15)+tf*16; h=0 hi, h=1 lo. Same (group,elem)->j map as the
// x-fragment loader => contraction correct for ANY internal HW k-order.
// ---------------------------------------------------------------------------
__global__ __launch_bounds__(128)
void ge_prepack(const float* __restrict__ Wy, uint4* __restrict__ wyp)
{
    const int e  = blockIdx.x * 128 + threadIdx.x;   // 0..8191
    const int l  = e & 63;
    const int h  = (e >> 6) & 1;
    const int tf = (e >> 7) & 1;
    const int ks = e >> 8;
    const int f  = (l & 15) + tf * 16;
    const int j0 = ks * 32 + (l >> 4) * 8;

    unsigned d[4];
#pragma unroll
    for (int p = 0; p < 4; ++p) {
        const float v0 = Wy[(size_t)(j0 + 2 * p) * kF + f];
        const float v1 = Wy[(size_t)(j0 + 2 * p + 1) * kF + f];
        unsigned short s0, s1;
        if (h == 0) {
            s0 = bf16_hi_bits(v0);
            s1 = bf16_hi_bits(v1);
        } else {
            s0 = bf16_hi_bits(v0 - bf16_bits_to_f(bf16_hi_bits(v0)));
            s1 = bf16_hi_bits(v1 - bf16_bits_to_f(bf16_hi_bits(v1)));
        }
        d[p] = (unsigned)s0 | ((unsigned)s1 << 16);
    }
    wyp[e] = make_uint4(d[0], d[1], d[2], d[3]);
}

// ---------------------------------------------------------------------------
// FUSED kernel: out[row,k] = [gate(x@Wy)] @ Wz^T, t kept in LDS.
// Phase 1 = r16's MFMA stage1, upgraded with T4 counted-vmcnt:
//   3-buffer rotation (tile t lives in buf t%3). Per tile:
//     STAGE(next)  ->  s_waitcnt vmcnt(6) lgkmcnt(0)  (drains CURRENT tile's
//     6 gl_lds, keeps next tile's 6 in flight ACROSS the barrier)  ->
//     raw s_barrier  ->  sched_barrier(0) (rule #18)  ->  compute.
//   r11-16 plateau at ~52us was the per-tile vmcnt(0) full drain (16x ~900cy
//   exposed latency); counted vmcnt is the documented fix (T3/T4).
//   Race audit: a buffer is rewritten 3 tiles after its read; >=1 full
//   barrier + per-tile lgkmcnt(0) drain separate read from rewrite.
// Phase 2 = round-5 ge_stage2 shape (proven no-spill): 2 passes x 2 k-cols,
//   Wz in 64 VGPR, t2 broadcast reads, float2 coalesced stores.
// LDS: x 3x16KB + B 3x8KB + t2 8KB = 80 KB -> 2 blocks/CU (8 waves).
// bf16-split: x*w ~= xh*wh + xh*wl + xl*wh (xl*wl dropped, ~2^-18 rel).
// D layout (verified m89 + rounds 11-16 passing): n=lane&15, m=(lane>>4)*4+reg.
// ---------------------------------------------------------------------------
__global__ __launch_bounds__(256, 2)
void ge_fused_mfma(const float* __restrict__ x,
                   const float* __restrict__ Wx,
                   const uint4* __restrict__ wyp,
                   const float* __restrict__ Wz,
                   float* __restrict__ out)
{
    __shared__ float4 xb4[3][1024];      // 48 KB: 64 rows x 16 slots / buf
    __shared__ uint4  bb4[3][512];       // 24 KB: 2 K-steps of frags / buf
    __shared__ float  t2[64][kF];        // 8 KB gated intermediate

    const int tid  = threadIdx.x;
    const int lane = tid & 63;
    const int wv   = tid >> 6;           // wave 0..3 = m-tile (16 rows)
    const int mrow = lane & 15;
    const int g    = lane >> 4;
    const int rowBase = blockIdx.x * 64;

    f32x4 c0 = {0.f, 0.f, 0.f, 0.f};
    f32x4 c1 = {0.f, 0.f, 0.f, 0.f};

    // x staging: instr q covers rows wv*16+q*4..+3, slot sc=lane&15;
    // source col16 = sc ^ (row&7) (rule #21: linear LDS dest, swizzled src)
#define STAGE(buf, ti)                                                  \
    {                                                                   \
        _Pragma("unroll")                                               \
        for (int q = 0; q < 4; ++q) {                                   \
            const int srow = wv * 16 + q * 4 + (lane >> 4);             \
            const int sc   = lane & 15;                                 \
            gl_lds16(x + (size_t)(rowBase + srow) * kJ + (ti) * 64      \
                       + 4 * (sc ^ (srow & 7)),                         \
                     &xb4[buf][(wv * 16 + q * 4) * 16]);                \
        }                                                               \
        _Pragma("unroll")                                               \
        for (int q = 0; q < 2; ++q)                                     \
            gl_lds16(wyp + (size_t)(ti) * 512 + wv * 128 + q * 64 + lane, \
                     &bb4[buf][wv * 128 + q * 64]);                     \
    }

    STAGE(0, 0)                          // tile 0 -> buf 0

#pragma unroll
    for (int ti = 0; ti < 16; ++ti) {
        const int bufR = ti % 3;
        if (ti < 15) {
            STAGE((ti + 1) % 3, ti + 1)  // 6 newest stay in flight
            asm volatile("s_waitcnt vmcnt(6) lgkmcnt(0)" ::: "memory");
        } else {
            asm volatile("s_waitcnt vmcnt(0) lgkmcnt(0)" ::: "memory");
        }
        asm volatile("s_barrier" ::: "memory");
        __builtin_amdgcn_sched_barrier(0);

#pragma unroll
        for (int kk2 = 0; kk2 < 2; ++kk2) {            // K-steps in tile
            const uint4 b0h = bb4[bufR][kk2 * 256 + lane];
            const uint4 b0l = bb4[bufR][kk2 * 256 + 64 + lane];
            const uint4 b1h = bb4[bufR][kk2 * 256 + 128 + lane];
            const uint4 b1l = bb4[bufR][kk2 * 256 + 192 + lane];

            const int s0 = (kk2 * 8 + g * 2) ^ (mrow & 7);
            const int s1 = (kk2 * 8 + g * 2 + 1) ^ (mrow & 7);
            const float4 xa = xb4[bufR][(wv * 16 + mrow) * 16 + s0];
            const float4 xc = xb4[bufR][(wv * 16 + mrow) * 16 + s1];
            const float xv[8] = {xa.x, xa.y, xa.z, xa.w,
                                 xc.x, xc.y, xc.z, xc.w};

            short8v ah, al;
#pragma unroll
            for (int e = 0; e < 8; ++e) {
                const unsigned short hb = bf16_hi_bits(xv[e]);
                const float hf = bf16_bits_to_f(hb);
                const unsigned short lb = bf16_hi_bits(xv[e] - hf);
                ah[e] = (short)hb;
                al[e] = (short)lb;
            }

            c0 = __builtin_amdgcn_mfma_f32_16x16x32_bf16(ah, as_s8(b0h), c0, 0, 0, 0);
            c1 = __builtin_amdgcn_mfma_f32_16x16x32_bf16(ah, as_s8(b1h), c1, 0, 0, 0);
            c0 = __builtin_amdgcn_mfma_f32_16x16x32_bf16(ah, as_s8(b0l), c0, 0, 0, 0);
            c1 = __builtin_amdgcn_mfma_f32_16x16x32_bf16(ah, as_s8(b1l), c1, 0, 0, 0);
            c0 = __builtin_amdgcn_mfma_f32_16x16x32_bf16(al, as_s8(b0h), c0, 0, 0, 0);
            c1 = __builtin_amdgcn_mfma_f32_16x16x32_bf16(al, as_s8(b1h), c1, 0, 0, 0);
        }
    }
#undef STAGE

    // phase-1 epilogue: gate by Wx, stash t tile in LDS.
    // D: n=lane&15, m=(lane>>4)*4+reg.
    {
        const int n = lane & 15;
#pragma unroll
        for (int r = 0; r < 4; ++r) {
            const int rl  = wv * 16 + g * 4 + r;
            const int i   = (rowBase + rl) & (kI - 1);
            t2[rl][n]      = c0[r] * Wx[(size_t)i * kF + n];
            t2[rl][16 + n] = c1[r] * Wx[(size_t)i * kF + 16 + n];
        }
    }
    __syncthreads();

    // ---------------- phase 2: out[row,k] = sum_f t2[row,f]*Wz[k,f] --------
    // 256 thr: 2 passes x 2 k-cols/thread (round-5 proven shape).
#pragma unroll
    for (int pass = 0; pass < 2; ++pass) {
        const int k0 = pass * 512 + tid * 2;
        float4 wa[8], wb[8];
#pragma unroll
        for (int q = 0; q < 8; ++q) {
            wa[q] = *reinterpret_cast<const float4*>(Wz + (size_t)k0 * kF + q * 4);
            wb[q] = *reinterpret_cast<const float4*>(Wz + (size_t)(k0 + 1) * kF + q * 4);
        }

        float* __restrict__ orow = out + (size_t)rowBase * kK + k0;
        for (int r = 0; r < 64; ++r) {
            float4 tr[8];
#pragma unroll
            for (int q = 0; q < 8; ++q)
                tr[q] = *reinterpret_cast<const float4*>(&t2[r][q * 4]);

            float a0 = 0.f, a1 = 0.f, b0 = 0.f, b1 = 0.f;
#pragma unroll
            for (int q = 0; q < 8; q += 2) {
                a0 = fmaf(tr[q].x, wa[q].x, a0);
                a0 = fmaf(tr[q].y, wa[q].y, a0);
                a0 = fmaf(tr[q].z, wa[q].z, a0);
                a0 = fmaf(tr[q].w, wa[q].w, a0);
                a1 = fmaf(tr[q + 1].x, wa[q + 1].x, a1);
                a1 = fmaf(tr[q + 1].y, wa[q + 1].y, a1);
                a1 = fmaf(tr[q + 1].z, wa[q + 1].z, a1);
                a1 = fmaf(tr[q + 1].w, wa[q + 1].w, a1);
                b0 = fmaf(tr[q].x, wb[q].x, b0);
                b0 = fmaf(tr[q].y, wb[q].y, b0);
                b0 = fmaf(tr[q].z, wb[q].z, b0);
                b0 = fmaf(tr[q].w, wb[q].w, b0);
                b1 = fmaf(tr[q + 1].x, wb[q + 1].x, b1);
                b1 = fmaf(tr[q + 1].y, wb[q + 1].y, b1);
                b1 = fmaf(tr[q + 1].z, wb[q + 1].z, b1);
                b1 = fmaf(tr[q + 1].w, wb[q + 1].w, b1);
            }
            float2 o;
            o.x = a0 + a1;
            o.y = b0 + b1;
            *reinterpret_cast<float2*>(orow + (size_t)r * kK) = o;
        }
    }
}

// ---------------------------------------------------------------------------
// Fallback: round-1 fused VALU kernel (proven correct) if ws too small.
// ---------------------------------------------------------------------------
__global__ __launch_bounds__(256, 2)
void gated_encoder_fused(const float* __restrict__ x,
                         const float* __restrict__ Wx,
                         const float* __restrict__ Wy,
                         const float* __restrict__ Wz,
                         float* __restrict__ out)
{
    __shared__ float t2[64][kF + 4];

    const int tid  = threadIdx.x;
    const int lane = tid & 63;
    const int wv   = tid >> 6;

    const int rloc = wv * 16 + (lane >> 2);
    const int row  = blockIdx.x * 64 + rloc;
    const int fg8  = (lane & 3) * 8;

    const float* __restrict__ xrow = x + (size_t)row * kJ;

    float acc[8];
#pragma unroll
    for (int u = 0; u < 8; ++u) acc[u] = 0.0f;

    for (int j = 0; j < kJ; j += 8) {
        const float4 xv0 = *reinterpret_cast<const float4*>(xrow + j);
        const float4 xv1 = *reinterpret_cast<const float4*>(xrow + j + 4);
        const float xs[8] = {xv0.x, xv0.y, xv0.z, xv0.w,
                             xv1.x, xv1.y, xv1.z, xv1.w};
#pragma unroll
        for (int u = 0; u < 8; ++u) {
            const float* wyp = Wy + (size_t)(j + u) * kF + fg8;
            const float4 w0 = *reinterpret_cast<const float4*>(wyp);
            const float4 w1 = *reinterpret_cast<const float4*>(wyp + 4);
            acc[0] = fmaf(xs[u], w0.x, acc[0]);
            acc[1] = fmaf(xs[u], w0.y, acc[1]);
            acc[2] = fmaf(xs[u], w0.z, acc[2]);
            acc[3] = fmaf(xs[u], w0.w, acc[3]);
            acc[4] = fmaf(xs[u], w1.x, acc[4]);
            acc[5] = fmaf(xs[u], w1.y, acc[5]);
            acc[6] = fmaf(xs[u], w1.z, acc[6]);
            acc[7] = fmaf(xs[u], w1.w, acc[7]);
        }
    }

    const int i = row & (kI - 1);
    const float* wxp = Wx + (size_t)i * kF + fg8;
    const float4 g0 = *reinterpret_cast<const float4*>(wxp);
    const float4 g1 = *reinterpret_cast<const float4*>(wxp + 4);
    float4 r0, r1;
    r0.x = acc[0] * g0.x;  r0.y = acc[1] * g0.y;
    r0.z = acc[2] * g0.z;  r0.w = acc[3] * g0.w;
    r1.x = acc[4] * g1.x;  r1.y = acc[5] * g1.y;
    r1.z = acc[6] * g1.z;  r1.w = acc[7] * g1.w;
    *reinterpret_cast<float4*>(&t2[rloc][fg8])     = r0;
    *reinterpret_cast<float4*>(&t2[rloc][fg8 + 4]) = r1;

    __syncthreads();

    const size_t outBase = (size_t)blockIdx.x * 64 * kK;

#pragma unroll
    for (int pass = 0; pass < 2; ++pass) {
        const int k1 = pass * 512 + tid;
        const int k2 = k1 + 256;
        const float* wz1 = Wz + (size_t)k1 * kF;
        const float* wz2 = Wz + (size_t)k2 * kF;
        float4 z1[8], z2[8];
#pragma unroll
        for (int m = 0; m < 8; ++m) {
            z1[m] = *reinterpret_cast<const float4*>(wz1 + 4 * m);
            z2[m] = *reinterpret_cast<const float4*>(wz2 + 4 * m);
        }
        for (int r = 0; r < 64; ++r) {
            float4 a1 = {0.f, 0.f, 0.f, 0.f};
            float4 a2 = {0.f, 0.f, 0.f, 0.f};
#pragma unroll
            for (int m = 0; m < 8; ++m) {
                const float4 tv = *reinterpret_cast<const float4*>(&t2[r][4 * m]);
                a1.x = fmaf(tv.x, z1[m].x, a1.x);
                a1.y = fmaf(tv.y, z1[m].y, a1.y);
                a1.z = fmaf(tv.z, z1[m].z, a1.z);
                a1.w = fmaf(tv.w, z1[m].w, a1.w);
                a2.x = fmaf(tv.x, z2[m].x, a2.x);
                a2.y = fmaf(tv.y, z2[m].y, a2.y);
                a2.z = fmaf(tv.z, z2[m].z, a2.z);
                a2.w = fmaf(tv.w, z2[m].w, a2.w);
            }
            out[outBase + (size_t)r * kK + k1] = (a1.x + a1.y) + (a1.z + a1.w);
            out[outBase + (size_t)r * kK + k2] = (a2.x + a2.y) + (a2.z + a2.w);
        }
    }
}

extern "C" void kernel_launch(void* const* d_in, const int* in_sizes, int n_in,
                              void* d_out, int out_size, void* d_ws, size_t ws_size,
                              hipStream_t stream) {
    const float* x  = (const float*)d_in[0];   // (B, I, J)
    const float* Wx = (const float*)d_in[1];   // (I, F)
    const float* Wy = (const float*)d_in[2];   // (J, F)
    const float* Wz = (const float*)d_in[3];   // (K, F)
    float* out = (float*)d_out;                // (B, I, K) f32

    const size_t wyBytes = 8192 * sizeof(uint4);                 // 128 KiB

    if (ws_size >= wyBytes && d_ws != nullptr) {
        uint4* wyp = (uint4*)d_ws;
        ge_prepack<<<dim3(64), 128, 0, stream>>>(Wy, wyp);
        ge_fused_mfma<<<dim3(kRows / 64), 256, 0, stream>>>(x, Wx, wyp, Wz, out);
    } else {
        gated_encoder_fused<<<dim3(kRows / 64), 256, 0, stream>>>(x, Wx, Wy, Wz, out);
    }
}

// Round 18
// 53.902 us; speedup vs baseline: 2.5170x; 1.3922x over previous
//
#include <hip/hip_runtime.h>
#include <hip/hip_bf16.h>
#include <string.h>

// GatedEncoderLayer: B=16, I=2048, J=1024, K=1024, F=32
// out[row,k] = sum_f [ (sum_j x[row,j]*Wy[j,f]) * Wx[row%I,f] ] * Wz[k,f]
constexpr int kI = 2048;
constexpr int kJ = 1024;
constexpr int kK = 1024;
constexpr int kF = 32;
constexpr int kRows = 16 * 2048;        // 32768

typedef __attribute__((ext_vector_type(8))) short short8v;
typedef __attribute__((ext_vector_type(4))) float f32x4;

__device__ inline unsigned short bf16_hi_bits(float v) {
    __hip_bfloat16 h = __float2bfloat16(v);      // RNE on gfx950
    unsigned short s;
    memcpy(&s, &h, 2);
    return s;
}
__device__ inline float bf16_bits_to_f(unsigned short s) {
    unsigned u = (unsigned)s << 16;
    float f;
    memcpy(&f, &u, 4);
    return f;
}
__device__ inline short8v as_s8(uint4 u) {
    union { uint4 a; short8v b; } c;
    c.a = u;
    return c.b;
}
// async global->LDS, 16B per lane; LDS dest = wave-uniform base + lane*16
__device__ inline void gl_lds16(const void* g, void* l) {
    __builtin_amdgcn_global_load_lds(
        (const __attribute__((address_space(1))) void*)g,
        (__attribute__((address_space(3))) void*)l,
        16, 0, 0);
}

// ---------------------------------------------------------------------------
// Prepack Wy -> fragment-ready bf16 hi/lo (128 KB). Entry e = ks*256 +
// tf*128 + h*64 + lane. Element short s -> j-elem; n-col f=(lane&15)+tf*16.
// ---------------------------------------------------------------------------
__global__ __launch_bounds__(128)
void ge_prepack(const float* __restrict__ Wy, uint4* __restrict__ wyp)
{
    const int e  = blockIdx.x * 128 + threadIdx.x;   // 0..8191
    const int l  = e & 63;
    const int h  = (e >> 6) & 1;
    const int tf = (e >> 7) & 1;
    const int ks = e >> 8;
    const int f  = (l & 15) + tf * 16;
    const int j0 = ks * 32 + (l >> 4) * 8;

    unsigned d[4];
#pragma unroll
    for (int p = 0; p < 4; ++p) {
        const float v0 = Wy[(size_t)(j0 + 2 * p) * kF + f];
        const float v1 = Wy[(size_t)(j0 + 2 * p + 1) * kF + f];
        unsigned short s0, s1;
        if (h == 0) {
            s0 = bf16_hi_bits(v0);
            s1 = bf16_hi_bits(v1);
        } else {
            s0 = bf16_hi_bits(v0 - bf16_bits_to_f(bf16_hi_bits(v0)));
            s1 = bf16_hi_bits(v1 - bf16_bits_to_f(bf16_hi_bits(v1)));
        }
        d[p] = (unsigned)s0 | ((unsigned)s1 << 16);
    }
    wyp[e] = make_uint4(d[0], d[1], d[2], d[3]);
}

// ---------------------------------------------------------------------------
// Prepack Wz -> B fragments for phase 2 (128 KB). For n-tile nt (16 k-cols):
// entry e = (nt*2+h)*64 + lane; n = nt*16 + (lane&15); element short s ->
// f = (lane>>4)*8 + s  — SAME (lane-group,elem)->f map as the A-side t-row
// loader, so the f-contraction is HW-k-order invariant.
// ---------------------------------------------------------------------------
__global__ __launch_bounds__(128)
void ge_prepack_z(const float* __restrict__ Wz, uint4* __restrict__ wzp)
{
    const int e  = blockIdx.x * 128 + threadIdx.x;   // 0..8191
    const int l  = e & 63;
    const int h  = (e >> 6) & 1;
    const int nt = e >> 7;                           // 0..63
    const int n  = nt * 16 + (l & 15);
    const int f0 = (l >> 4) * 8;

    unsigned d[4];
#pragma unroll
    for (int p = 0; p < 4; ++p) {
        const float v0 = Wz[(size_t)n * kF + f0 + 2 * p];
        const float v1 = Wz[(size_t)n * kF + f0 + 2 * p + 1];
        unsigned short s0, s1;
        if (h == 0) {
            s0 = bf16_hi_bits(v0);
            s1 = bf16_hi_bits(v1);
        } else {
            s0 = bf16_hi_bits(v0 - bf16_bits_to_f(bf16_hi_bits(v0)));
            s1 = bf16_hi_bits(v1 - bf16_bits_to_f(bf16_hi_bits(v1)));
        }
        d[p] = (unsigned)s0 | ((unsigned)s1 << 16);
    }
    wzp[e] = make_uint4(d[0], d[1], d[2], d[3]);
}

// ---------------------------------------------------------------------------
// FUSED all-MFMA kernel.
// Phase 1 (r17, proven): x@Wy with gl_lds staging, 3-buf rotation, counted
//   vmcnt(6) + raw s_barrier + sched_barrier (T4).  ~15us issue.
// Phase 2 (NEW, r17 postmortem): out = t@Wz^T via MFMA. r17's VALU phase 2
//   issued 1024 broadcast ds_read_b128/thread (~20us/CU LDS pipe) + 13.6us
//   FMA issue — dominant cost. Now: A-frag = t-row, 2 LDS reads + 1 cvt per
//   thread TOTAL (reused over 64 n-tiles); B staged 16-ntiles/chunk (32KB)
//   via gl_lds, 4 chunks; 3 MFMA + 4 stores per n-tile.
// LDS aliased in one 72KB block (2 blocks/CU):
//   phase1: xb 48KB + bb 24KB;  phase2: zb 32KB (in xb) + t2 9KB (in bb).
// bf16-split both phases: a*b ~= ah*bh + ah*bl + al*bh.
// D layout (verified m89 + r11-17 passing): n=lane&15, m=(lane>>4)*4+reg.
// ---------------------------------------------------------------------------
__global__ __launch_bounds__(256, 2)
void ge_fused_mfma(const float* __restrict__ x,
                   const float* __restrict__ Wx,
                   const uint4* __restrict__ wyp,
                   const uint4* __restrict__ wzp,
                   float* __restrict__ out)
{
    __shared__ __align__(16) char smem[73728];       // 72 KB
    float4* xb4 = reinterpret_cast<float4*>(smem);           // [3*1024]
    uint4*  bb4 = reinterpret_cast<uint4*>(smem + 49152);    // [3*512]
    uint4*  zb  = reinterpret_cast<uint4*>(smem);            // [2048] ph2
    float*  t2  = reinterpret_cast<float*>(smem + 49152);    // [64*36] ph2

    const int tid  = threadIdx.x;
    const int lane = tid & 63;
    const int wv   = tid >> 6;           // wave 0..3 = m-tile (16 rows)
    const int mrow = lane & 15;
    const int g    = lane >> 4;
    const int rowBase = blockIdx.x * 64;

    f32x4 c0 = {0.f, 0.f, 0.f, 0.f};
    f32x4 c1 = {0.f, 0.f, 0.f, 0.f};

#define STAGE(buf, ti)                                                  \
    {                                                                   \
        _Pragma("unroll")                                               \
        for (int q = 0; q < 4; ++q) {                                   \
            const int srow = wv * 16 + q * 4 + (lane >> 4);             \
            const int sc   = lane & 15;                                 \
            gl_lds16(x + (size_t)(rowBase + srow) * kJ + (ti) * 64      \
                       + 4 * (sc ^ (srow & 7)),                         \
                     &xb4[(buf) * 1024 + (wv * 16 + q * 4) * 16]);      \
        }                                                               \
        _Pragma("unroll")                                               \
        for (int q = 0; q < 2; ++q)                                     \
            gl_lds16(wyp + (size_t)(ti) * 512 + wv * 128 + q * 64 + lane, \
                     &bb4[(buf) * 512 + wv * 128 + q * 64]);            \
    }

    STAGE(0, 0)

#pragma unroll
    for (int ti = 0; ti < 16; ++ti) {
        const int bufR = ti % 3;
        if (ti < 15) {
            STAGE((ti + 1) % 3, ti + 1)
            asm volatile("s_waitcnt vmcnt(6) lgkmcnt(0)" ::: "memory");
        } else {
            asm volatile("s_waitcnt vmcnt(0) lgkmcnt(0)" ::: "memory");
        }
        asm volatile("s_barrier" ::: "memory");
        __builtin_amdgcn_sched_barrier(0);

#pragma unroll
        for (int kk2 = 0; kk2 < 2; ++kk2) {
            const uint4 b0h = bb4[bufR * 512 + kk2 * 256 + lane];
            const uint4 b0l = bb4[bufR * 512 + kk2 * 256 + 64 + lane];
            const uint4 b1h = bb4[bufR * 512 + kk2 * 256 + 128 + lane];
            const uint4 b1l = bb4[bufR * 512 + kk2 * 256 + 192 + lane];

            const int s0 = (kk2 * 8 + g * 2) ^ (mrow & 7);
            const int s1 = (kk2 * 8 + g * 2 + 1) ^ (mrow & 7);
            const float4 xa = xb4[bufR * 1024 + (wv * 16 + mrow) * 16 + s0];
            const float4 xc = xb4[bufR * 1024 + (wv * 16 + mrow) * 16 + s1];
            const float xv[8] = {xa.x, xa.y, xa.z, xa.w,
                                 xc.x, xc.y, xc.z, xc.w};

            short8v ah, al;
#pragma unroll
            for (int e = 0; e < 8; ++e) {
                const unsigned short hb = bf16_hi_bits(xv[e]);
                const float hf = bf16_bits_to_f(hb);
                const unsigned short lb = bf16_hi_bits(xv[e] - hf);
                ah[e] = (short)hb;
                al[e] = (short)lb;
            }

            c0 = __builtin_amdgcn_mfma_f32_16x16x32_bf16(ah, as_s8(b0h), c0, 0, 0, 0);
            c1 = __builtin_amdgcn_mfma_f32_16x16x32_bf16(ah, as_s8(b1h), c1, 0, 0, 0);
            c0 = __builtin_amdgcn_mfma_f32_16x16x32_bf16(ah, as_s8(b0l), c0, 0, 0, 0);
            c1 = __builtin_amdgcn_mfma_f32_16x16x32_bf16(ah, as_s8(b1l), c1, 0, 0, 0);
            c0 = __builtin_amdgcn_mfma_f32_16x16x32_bf16(al, as_s8(b0h), c0, 0, 0, 0);
            c1 = __builtin_amdgcn_mfma_f32_16x16x32_bf16(al, as_s8(b1h), c1, 0, 0, 0);
        }
    }
#undef STAGE

    // --- epilogue of phase 1: gate by Wx, write t2 (aliases bb4) ---
    __syncthreads();                     // all bb4/xb4 reads done
    {
        const int n = lane & 15;
#pragma unroll
        for (int r = 0; r < 4; ++r) {
            const int rl = wv * 16 + g * 4 + r;
            const int i  = (rowBase + rl) & (kI - 1);
            t2[rl * 36 + n]      = c0[r] * Wx[(size_t)i * kF + n];
            t2[rl * 36 + 16 + n] = c1[r] * Wx[(size_t)i * kF + 16 + n];
        }
    }
    __syncthreads();

    // --- phase 2: out = t2 @ Wz^T, MFMA, one K-step (f=32) per n-tile ---
    // A-frag: lane = (row mrow of wave's group, f-octet g), loaded ONCE.
    short8v th, tl;
    {
        const float* trow = &t2[(wv * 16 + mrow) * 36 + g * 8];
        const float4 ta = *reinterpret_cast<const float4*>(trow);
        const float4 tb = *reinterpret_cast<const float4*>(trow + 4);
        const float tv[8] = {ta.x, ta.y, ta.z, ta.w, tb.x, tb.y, tb.z, tb.w};
#pragma unroll
        for (int e = 0; e < 8; ++e) {
            const unsigned short hb = bf16_hi_bits(tv[e]);
            const float hf = bf16_bits_to_f(hb);
            const unsigned short lb = bf16_hi_bits(tv[e] - hf);
            th[e] = (short)hb;
            tl[e] = (short)lb;
        }
    }

    const int n = lane & 15;
#pragma unroll
    for (int ch = 0; ch < 4; ++ch) {
        __syncthreads();                 // zb free (prev chunk read / xb done)
        // stage 16 n-tiles = 2048 uint4 = 32 KB: 8 gl_lds per wave
#pragma unroll
        for (int q = 0; q < 8; ++q)
            gl_lds16(wzp + (size_t)ch * 2048 + wv * 512 + q * 64 + lane,
                     &zb[wv * 512 + q * 64]);
        asm volatile("s_waitcnt vmcnt(0)" ::: "memory");
        __syncthreads();                 // chunk visible to all waves

#pragma unroll
        for (int ntl = 0; ntl < 16; ++ntl) {
            const uint4 bh = zb[ntl * 128 + lane];
            const uint4 bl = zb[ntl * 128 + 64 + lane];

            f32x4 c = {0.f, 0.f, 0.f, 0.f};
            c = __builtin_amdgcn_mfma_f32_16x16x32_bf16(th, as_s8(bh), c, 0, 0, 0);
            c = __builtin_amdgcn_mfma_f32_16x16x32_bf16(th, as_s8(bl), c, 0, 0, 0);
            c = __builtin_amdgcn_mfma_f32_16x16x32_bf16(tl, as_s8(bh), c, 0, 0, 0);

            const int k = ch * 256 + ntl * 16 + n;
#pragma unroll
            for (int r = 0; r < 4; ++r) {
                const int row = rowBase + wv * 16 + g * 4 + r;
                out[(size_t)row * kK + k] = c[r];
            }
        }
    }
}

// ---------------------------------------------------------------------------
// Fallback: round-1 fused VALU kernel (proven correct) if ws too small.
// ---------------------------------------------------------------------------
__global__ __launch_bounds__(256, 2)
void gated_encoder_fused(const float* __restrict__ x,
                         const float* __restrict__ Wx,
                         const float* __restrict__ Wy,
                         const float* __restrict__ Wz,
                         float* __restrict__ out)
{
    __shared__ float t2[64][kF + 4];

    const int tid  = threadIdx.x;
    const int lane = tid & 63;
    const int wv   = tid >> 6;

    const int rloc = wv * 16 + (lane >> 2);
    const int row  = blockIdx.x * 64 + rloc;
    const int fg8  = (lane & 3) * 8;

    const float* __restrict__ xrow = x + (size_t)row * kJ;

    float acc[8];
#pragma unroll
    for (int u = 0; u < 8; ++u) acc[u] = 0.0f;

    for (int j = 0; j < kJ; j += 8) {
        const float4 xv0 = *reinterpret_cast<const float4*>(xrow + j);
        const float4 xv1 = *reinterpret_cast<const float4*>(xrow + j + 4);
        const float xs[8] = {xv0.x, xv0.y, xv0.z, xv0.w,
                             xv1.x, xv1.y, xv1.z, xv1.w};
#pragma unroll
        for (int u = 0; u < 8; ++u) {
            const float* wyp = Wy + (size_t)(j + u) * kF + fg8;
            const float4 w0 = *reinterpret_cast<const float4*>(wyp);
            const float4 w1 = *reinterpret_cast<const float4*>(wyp + 4);
            acc[0] = fmaf(xs[u], w0.x, acc[0]);
            acc[1] = fmaf(xs[u], w0.y, acc[1]);
            acc[2] = fmaf(xs[u], w0.z, acc[2]);
            acc[3] = fmaf(xs[u], w0.w, acc[3]);
            acc[4] = fmaf(xs[u], w1.x, acc[4]);
            acc[5] = fmaf(xs[u], w1.y, acc[5]);
            acc[6] = fmaf(xs[u], w1.z, acc[6]);
            acc[7] = fmaf(xs[u], w1.w, acc[7]);
        }
    }

    const int i = row & (kI - 1);
    const float* wxp = Wx + (size_t)i * kF + fg8;
    const float4 g0 = *reinterpret_cast<const float4*>(wxp);
    const float4 g1 = *reinterpret_cast<const float4*>(wxp + 4);
    float4 r0, r1;
    r0.x = acc[0] * g0.x;  r0.y = acc[1] * g0.y;
    r0.z = acc[2] * g0.z;  r0.w = acc[3] * g0.w;
    r1.x = acc[4] * g1.x;  r1.y = acc[5] * g1.y;
    r1.z = acc[6] * g1.z;  r1.w = acc[7] * g1.w;
    *reinterpret_cast<float4*>(&t2[rloc][fg8])     = r0;
    *reinterpret_cast<float4*>(&t2[rloc][fg8 + 4]) = r1;

    __syncthreads();

    const size_t outBase = (size_t)blockIdx.x * 64 * kK;

#pragma unroll
    for (int pass = 0; pass < 2; ++pass) {
        const int k1 = pass * 512 + tid;
        const int k2 = k1 + 256;
        const float* wz1 = Wz + (size_t)k1 * kF;
        const float* wz2 = Wz + (size_t)k2 * kF;
        float4 z1[8], z2[8];
#pragma unroll
        for (int m = 0; m < 8; ++m) {
            z1[m] = *reinterpret_cast<const float4*>(wz1 + 4 * m);
            z2[m] = *reinterpret_cast<const float4*>(wz2 + 4 * m);
        }
        for (int r = 0; r < 64; ++r) {
            float4 a1 = {0.f, 0.f, 0.f, 0.f};
            float4 a2 = {0.f, 0.f, 0.f, 0.f};
#pragma unroll
            for (int m = 0; m < 8; ++m) {
                const float4 tv = *reinterpret_cast<const float4*>(&t2[r][4 * m]);
                a1.x = fmaf(tv.x, z1[m].x, a1.x);
                a1.y = fmaf(tv.y, z1[m].y, a1.y);
                a1.z = fmaf(tv.z, z1[m].z, a1.z);
                a1.w = fmaf(tv.w, z1[m].w, a1.w);
                a2.x = fmaf(tv.x, z2[m].x, a2.x);
                a2.y = fmaf(tv.y, z2[m].y, a2.y);
                a2.z = fmaf(tv.z, z2[m].z, a2.z);
                a2.w = fmaf(tv.w, z2[m].w, a2.w);
            }
            out[outBase + (size_t)r * kK + k1] = (a1.x + a1.y) + (a1.z + a1.w);
            out[outBase + (size_t)r * kK + k2] = (a2.x + a2.y) + (a2.z + a2.w);
        }
    }
}

extern "C" void kernel_launch(void* const* d_in, const int* in_sizes, int n_in,
                              void* d_out, int out_size, void* d_ws, size_t ws_size,
                              hipStream_t stream) {
    const float* x  = (const float*)d_in[0];   // (B, I, J)
    const float* Wx = (const float*)d_in[1];   // (I, F)
    const float* Wy = (const float*)d_in[2];   // (J, F)
    const float* Wz = (const float*)d_in[3];   // (K, F)
    float* out = (float*)d_out;                // (B, I, K) f32

    const size_t wyBytes = 8192 * sizeof(uint4);   // 128 KiB
    const size_t wzBytes = 8192 * sizeof(uint4);   // 128 KiB

    if (ws_size >= wyBytes + wzBytes && d_ws != nullptr) {
        uint4* wyp = (uint4*)d_ws;
        uint4* wzp = (uint4*)((char*)d_ws + wyBytes);
        ge_prepack<<<dim3(64), 128, 0, stream>>>(Wy, wyp);
        ge_prepack_z<<<dim3(64), 128, 0, stream>>>(Wz, wzp);
        ge_fused_mfma<<<dim3(kRows / 64), 256, 0, stream>>>(x, Wx, wyp, wzp, out);
    } else {
        gated_encoder_fused<<<dim3(kRows / 64), 256, 0, stream>>>(x, Wx, Wy, Wz, out);
    }
}

// Round 19
// 51.964 us; speedup vs baseline: 2.6109x; 1.0373x over previous
//
#include <hip/hip_runtime.h>
#include <hip/hip_bf16.h>
#include <string.h>

// GatedEncoderLayer: B=16, I=2048, J=1024, K=1024, F=32
// out[row,k] = sum_f [ (sum_j x[row,j]*Wy[j,f]) * Wx[row%I,f] ] * Wz[k,f]
constexpr int kI = 2048;
constexpr int kJ = 1024;
constexpr int kK = 1024;
constexpr int kF = 32;
constexpr int kRows = 16 * 2048;        // 32768

typedef __attribute__((ext_vector_type(8))) short short8v;
typedef __attribute__((ext_vector_type(4))) float f32x4;

__device__ inline unsigned short bf16_hi_bits(float v) {
    __hip_bfloat16 h = __float2bfloat16(v);      // RNE on gfx950
    unsigned short s;
    memcpy(&s, &h, 2);
    return s;
}
__device__ inline float bf16_bits_to_f(unsigned short s) {
    unsigned u = (unsigned)s << 16;
    float f;
    memcpy(&f, &u, 4);
    return f;
}
__device__ inline short8v as_s8(uint4 u) {
    union { uint4 a; short8v b; } c;
    c.a = u;
    return c.b;
}
// async global->LDS, 16B per lane; LDS dest = wave-uniform base + lane*16
__device__ inline void gl_lds16(const void* g, void* l) {
    __builtin_amdgcn_global_load_lds(
        (const __attribute__((address_space(1))) void*)g,
        (__attribute__((address_space(3))) void*)l,
        16, 0, 0);
}

// ---------------------------------------------------------------------------
// Merged prepack (one launch): e<8192 -> Wy fragments, e>=8192 -> Wz frags.
// Wy entry e = ks*256 + tf*128 + h*64 + lane: elem s -> j; n-col f.
// Wz entry e' = (nt*2+h)*64 + lane: n = nt*16+(lane&15), f = (lane>>4)*8+s
//   — SAME (lane-group,elem)->f map as phase-2's A-side t-row loader.
// ---------------------------------------------------------------------------
__global__ __launch_bounds__(128)
void ge_prepack_all(const float* __restrict__ Wy, const float* __restrict__ Wz,
                    uint4* __restrict__ wyp, uint4* __restrict__ wzp)
{
    const int eg = blockIdx.x * 128 + threadIdx.x;   // 0..16383
    if (eg < 8192) {
        const int e  = eg;
        const int l  = e & 63;
        const int h  = (e >> 6) & 1;
        const int tf = (e >> 7) & 1;
        const int ks = e >> 8;
        const int f  = (l & 15) + tf * 16;
        const int j0 = ks * 32 + (l >> 4) * 8;
        unsigned d[4];
#pragma unroll
        for (int p = 0; p < 4; ++p) {
            const float v0 = Wy[(size_t)(j0 + 2 * p) * kF + f];
            const float v1 = Wy[(size_t)(j0 + 2 * p + 1) * kF + f];
            unsigned short s0, s1;
            if (h == 0) {
                s0 = bf16_hi_bits(v0);
                s1 = bf16_hi_bits(v1);
            } else {
                s0 = bf16_hi_bits(v0 - bf16_bits_to_f(bf16_hi_bits(v0)));
                s1 = bf16_hi_bits(v1 - bf16_bits_to_f(bf16_hi_bits(v1)));
            }
            d[p] = (unsigned)s0 | ((unsigned)s1 << 16);
        }
        wyp[e] = make_uint4(d[0], d[1], d[2], d[3]);
    } else {
        const int e  = eg - 8192;
        const int l  = e & 63;
        const int h  = (e >> 6) & 1;
        const int nt = e >> 7;                       // 0..63
        const int n  = nt * 16 + (l & 15);
        const int f0 = (l >> 4) * 8;
        unsigned d[4];
#pragma unroll
        for (int p = 0; p < 4; ++p) {
            const float v0 = Wz[(size_t)n * kF + f0 + 2 * p];
            const float v1 = Wz[(size_t)n * kF + f0 + 2 * p + 1];
            unsigned short s0, s1;
            if (h == 0) {
                s0 = bf16_hi_bits(v0);
                s1 = bf16_hi_bits(v1);
            } else {
                s0 = bf16_hi_bits(v0 - bf16_bits_to_f(bf16_hi_bits(v0)));
                s1 = bf16_hi_bits(v1 - bf16_bits_to_f(bf16_hi_bits(v1)));
            }
            d[p] = (unsigned)s0 | ((unsigned)s1 << 16);
        }
        wzp[e] = make_uint4(d[0], d[1], d[2], d[3]);
    }
}

// ---------------------------------------------------------------------------
// FUSED all-MFMA kernel (r18 structure + depth-2 pipelines).
// Phase 1: x@Wy, gl_lds staging, 3-buf rotation, DEPTH-2 counted vmcnt:
//   prologue stages tiles 0,1; per tile: wait vmcnt(6) (drains stage(t),
//   keeps stage(t+1) in flight) -> s_barrier -> STAGE(t+2) -> compute(t).
//   stage(t) thus has ~2 tiles of compute + 2 barriers to complete (r18's
//   depth-1 exposed ~700cy/tile). Race-free: STAGE(t+2) targets buf
//   (t-1)%3 whose last reader finished before this tile's barrier.
// Phase 2: out = t2 @ Wz^T via MFMA, zb DOUBLE-buffered (2x32KB):
//   wait vmcnt(8) -> barrier -> STAGE_Z(ch+1) -> compute(ch).
// LDS (75 KB, 2 blocks/CU): ph1 xb 48K + bb 24K; ph2 zb 64K + t2 9.2K @64K+.
//   All repurposing crosses a __syncthreads.
// bf16-split both phases: a*b ~= ah*bh + ah*bl + al*bh (~2^-16 rel).
// D layout (verified m89 + r11-18 passing): n=lane&15, m=(lane>>4)*4+reg.
// ---------------------------------------------------------------------------
__global__ __launch_bounds__(256, 2)
void ge_fused_mfma(const float* __restrict__ x,
                   const float* __restrict__ Wx,
                   const uint4* __restrict__ wyp,
                   const uint4* __restrict__ wzp,
                   float* __restrict__ out)
{
    __shared__ __align__(16) char smem[75776];               // 74 KB
    float4* xb4 = reinterpret_cast<float4*>(smem);           // ph1 [3*1024]
    uint4*  bb4 = reinterpret_cast<uint4*>(smem + 49152);    // ph1 [3*512]
    uint4*  zb  = reinterpret_cast<uint4*>(smem);            // ph2 [2*2048]
    float*  t2  = reinterpret_cast<float*>(smem + 65536);    // ph2 [64*36]

    const int tid  = threadIdx.x;
    const int lane = tid & 63;
    const int wv   = tid >> 6;           // wave 0..3 = m-tile (16 rows)
    const int mrow = lane & 15;
    const int g    = lane >> 4;
    const int rowBase = blockIdx.x * 64;

    f32x4 c0 = {0.f, 0.f, 0.f, 0.f};
    f32x4 c1 = {0.f, 0.f, 0.f, 0.f};

#define STAGE(buf, ti)                                                  \
    {                                                                   \
        _Pragma("unroll")                                               \
        for (int q = 0; q < 4; ++q) {                                   \
            const int srow = wv * 16 + q * 4 + (lane >> 4);             \
            const int sc   = lane & 15;                                 \
            gl_lds16(x + (size_t)(rowBase + srow) * kJ + (ti) * 64      \
                       + 4 * (sc ^ (srow & 7)),                         \
                     &xb4[(buf) * 1024 + (wv * 16 + q * 4) * 16]);      \
        }                                                               \
        _Pragma("unroll")                                               \
        for (int q = 0; q < 2; ++q)                                     \
            gl_lds16(wyp + (size_t)(ti) * 512 + wv * 128 + q * 64 + lane, \
                     &bb4[(buf) * 512 + wv * 128 + q * 64]);            \
    }

    STAGE(0, 0)
    STAGE(1, 1)                          // depth-2 prologue (12 in flight)

#pragma unroll
    for (int ti = 0; ti < 16; ++ti) {
        const int bufR = ti % 3;
        if (ti < 15) {
            // drain stage(ti) (oldest 6), keep stage(ti+1)'s 6 in flight
            asm volatile("s_waitcnt vmcnt(6) lgkmcnt(0)" ::: "memory");
        } else {
            asm volatile("s_waitcnt vmcnt(0) lgkmcnt(0)" ::: "memory");
        }
        asm volatile("s_barrier" ::: "memory");
        __builtin_amdgcn_sched_barrier(0);
        if (ti < 14) { STAGE((ti + 2) % 3, ti + 2) }   // 2 tiles ahead

#pragma unroll
        for (int kk2 = 0; kk2 < 2; ++kk2) {
            const uint4 b0h = bb4[bufR * 512 + kk2 * 256 + lane];
            const uint4 b0l = bb4[bufR * 512 + kk2 * 256 + 64 + lane];
            const uint4 b1h = bb4[bufR * 512 + kk2 * 256 + 128 + lane];
            const uint4 b1l = bb4[bufR * 512 + kk2 * 256 + 192 + lane];

            const int s0 = (kk2 * 8 + g * 2) ^ (mrow & 7);
            const int s1 = (kk2 * 8 + g * 2 + 1) ^ (mrow & 7);
            const float4 xa = xb4[bufR * 1024 + (wv * 16 + mrow) * 16 + s0];
            const float4 xc = xb4[bufR * 1024 + (wv * 16 + mrow) * 16 + s1];
            const float xv[8] = {xa.x, xa.y, xa.z, xa.w,
                                 xc.x, xc.y, xc.z, xc.w};

            short8v ah, al;
#pragma unroll
            for (int e = 0; e < 8; ++e) {
                const unsigned short hb = bf16_hi_bits(xv[e]);
                const float hf = bf16_bits_to_f(hb);
                const unsigned short lb = bf16_hi_bits(xv[e] - hf);
                ah[e] = (short)hb;
                al[e] = (short)lb;
            }

            c0 = __builtin_amdgcn_mfma_f32_16x16x32_bf16(ah, as_s8(b0h), c0, 0, 0, 0);
            c1 = __builtin_amdgcn_mfma_f32_16x16x32_bf16(ah, as_s8(b1h), c1, 0, 0, 0);
            c0 = __builtin_amdgcn_mfma_f32_16x16x32_bf16(ah, as_s8(b0l), c0, 0, 0, 0);
            c1 = __builtin_amdgcn_mfma_f32_16x16x32_bf16(ah, as_s8(b1l), c1, 0, 0, 0);
            c0 = __builtin_amdgcn_mfma_f32_16x16x32_bf16(al, as_s8(b0h), c0, 0, 0, 0);
            c1 = __builtin_amdgcn_mfma_f32_16x16x32_bf16(al, as_s8(b1h), c1, 0, 0, 0);
        }
    }
#undef STAGE

    // --- phase-1 epilogue: gate by Wx, write t2 (aliases upper bb4) ---
    __syncthreads();                     // all xb4/bb4 reads done
    {
        const int n = lane & 15;
#pragma unroll
        for (int r = 0; r < 4; ++r) {
            const int rl = wv * 16 + g * 4 + r;
            const int i  = (rowBase + rl) & (kI - 1);
            t2[rl * 36 + n]      = c0[r] * Wx[(size_t)i * kF + n];
            t2[rl * 36 + 16 + n] = c1[r] * Wx[(size_t)i * kF + 16 + n];
        }
    }
    __syncthreads();

    // --- phase 2: out = t2 @ Wz^T, MFMA, double-buffered zb ---
#define STAGE_Z(buf, ch)                                                \
    _Pragma("unroll")                                                   \
    for (int q = 0; q < 8; ++q)                                         \
        gl_lds16(wzp + (size_t)(ch) * 2048 + wv * 512 + q * 64 + lane,  \
                 &zb[(buf) * 2048 + wv * 512 + q * 64]);

    STAGE_Z(0, 0)                        // overlaps t-row read/cvt below

    short8v th, tl;
    {
        const float* trow = &t2[(wv * 16 + mrow) * 36 + g * 8];
        const float4 ta = *reinterpret_cast<const float4*>(trow);
        const float4 tb = *reinterpret_cast<const float4*>(trow + 4);
        const float tv[8] = {ta.x, ta.y, ta.z, ta.w, tb.x, tb.y, tb.z, tb.w};
#pragma unroll
        for (int e = 0; e < 8; ++e) {
            const unsigned short hb = bf16_hi_bits(tv[e]);
            const float hf = bf16_bits_to_f(hb);
            const unsigned short lb = bf16_hi_bits(tv[e] - hf);
            th[e] = (short)hb;
            tl[e] = (short)lb;
        }
    }

    const int n = lane & 15;
#pragma unroll
    for (int ch = 0; ch < 4; ++ch) {
        if (ch < 3) {
            asm volatile("s_waitcnt vmcnt(8) lgkmcnt(0)" ::: "memory");
        } else {
            asm volatile("s_waitcnt vmcnt(0) lgkmcnt(0)" ::: "memory");
        }
        asm volatile("s_barrier" ::: "memory");
        __builtin_amdgcn_sched_barrier(0);
        if (ch < 3) { STAGE_Z((ch + 1) & 1, ch + 1) }

#pragma unroll
        for (int ntl = 0; ntl < 16; ++ntl) {
            const uint4 bh = zb[(ch & 1) * 2048 + ntl * 128 + lane];
            const uint4 bl = zb[(ch & 1) * 2048 + ntl * 128 + 64 + lane];

            f32x4 c = {0.f, 0.f, 0.f, 0.f};
            c = __builtin_amdgcn_mfma_f32_16x16x32_bf16(th, as_s8(bh), c, 0, 0, 0);
            c = __builtin_amdgcn_mfma_f32_16x16x32_bf16(th, as_s8(bl), c, 0, 0, 0);
            c = __builtin_amdgcn_mfma_f32_16x16x32_bf16(tl, as_s8(bh), c, 0, 0, 0);

            const int k = ch * 256 + ntl * 16 + n;
#pragma unroll
            for (int r = 0; r < 4; ++r) {
                const int row = rowBase + wv * 16 + g * 4 + r;
                out[(size_t)row * kK + k] = c[r];
            }
        }
    }
#undef STAGE_Z
}

// ---------------------------------------------------------------------------
// Fallback: round-1 fused VALU kernel (proven correct) if ws too small.
// ---------------------------------------------------------------------------
__global__ __launch_bounds__(256, 2)
void gated_encoder_fused(const float* __restrict__ x,
                         const float* __restrict__ Wx,
                         const float* __restrict__ Wy,
                         const float* __restrict__ Wz,
                         float* __restrict__ out)
{
    __shared__ float t2[64][kF + 4];

    const int tid  = threadIdx.x;
    const int lane = tid & 63;
    const int wv   = tid >> 6;

    const int rloc = wv * 16 + (lane >> 2);
    const int row  = blockIdx.x * 64 + rloc;
    const int fg8  = (lane & 3) * 8;

    const float* __restrict__ xrow = x + (size_t)row * kJ;

    float acc[8];
#pragma unroll
    for (int u = 0; u < 8; ++u) acc[u] = 0.0f;

    for (int j = 0; j < kJ; j += 8) {
        const float4 xv0 = *reinterpret_cast<const float4*>(xrow + j);
        const float4 xv1 = *reinterpret_cast<const float4*>(xrow + j + 4);
        const float xs[8] = {xv0.x, xv0.y, xv0.z, xv0.w,
                             xv1.x, xv1.y, xv1.z, xv1.w};
#pragma unroll
        for (int u = 0; u < 8; ++u) {
            const float* wyp = Wy + (size_t)(j + u) * kF + fg8;
            const float4 w0 = *reinterpret_cast<const float4*>(wyp);
            const float4 w1 = *reinterpret_cast<const float4*>(wyp + 4);
            acc[0] = fmaf(xs[u], w0.x, acc[0]);
            acc[1] = fmaf(xs[u], w0.y, acc[1]);
            acc[2] = fmaf(xs[u], w0.z, acc[2]);
            acc[3] = fmaf(xs[u], w0.w, acc[3]);
            acc[4] = fmaf(xs[u], w1.x, acc[4]);
            acc[5] = fmaf(xs[u], w1.y, acc[5]);
            acc[6] = fmaf(xs[u], w1.z, acc[6]);
            acc[7] = fmaf(xs[u], w1.w, acc[7]);
        }
    }

    const int i = row & (kI - 1);
    const float* wxp = Wx + (size_t)i * kF + fg8;
    const float4 g0 = *reinterpret_cast<const float4*>(wxp);
    const float4 g1 = *reinterpret_cast<const float4*>(wxp + 4);
    float4 r0, r1;
    r0.x = acc[0] * g0.x;  r0.y = acc[1] * g0.y;
    r0.z = acc[2] * g0.z;  r0.w = acc[3] * g0.w;
    r1.x = acc[4] * g1.x;  r1.y = acc[5] * g1.y;
    r1.z = acc[6] * g1.z;  r1.w = acc[7] * g1.w;
    *reinterpret_cast<float4*>(&t2[rloc][fg8])     = r0;
    *reinterpret_cast<float4*>(&t2[rloc][fg8 + 4]) = r1;

    __syncthreads();

    const size_t outBase = (size_t)blockIdx.x * 64 * kK;

#pragma unroll
    for (int pass = 0; pass < 2; ++pass) {
        const int k1 = pass * 512 + tid;
        const int k2 = k1 + 256;
        const float* wz1 = Wz + (size_t)k1 * kF;
        const float* wz2 = Wz + (size_t)k2 * kF;
        float4 z1[8], z2[8];
#pragma unroll
        for (int m = 0; m < 8; ++m) {
            z1[m] = *reinterpret_cast<const float4*>(wz1 + 4 * m);
            z2[m] = *reinterpret_cast<const float4*>(wz2 + 4 * m);
        }
        for (int r = 0; r < 64; ++r) {
            float4 a1 = {0.f, 0.f, 0.f, 0.f};
            float4 a2 = {0.f, 0.f, 0.f, 0.f};
#pragma unroll
            for (int m = 0; m < 8; ++m) {
                const float4 tv = *reinterpret_cast<const float4*>(&t2[r][4 * m]);
                a1.x = fmaf(tv.x, z1[m].x, a1.x);
                a1.y = fmaf(tv.y, z1[m].y, a1.y);
                a1.z = fmaf(tv.z, z1[m].z, a1.z);
                a1.w = fmaf(tv.w, z1[m].w, a1.w);
                a2.x = fmaf(tv.x, z2[m].x, a2.x);
                a2.y = fmaf(tv.y, z2[m].y, a2.y);
                a2.z = fmaf(tv.z, z2[m].z, a2.z);
                a2.w = fmaf(tv.w, z2[m].w, a2.w);
            }
            out[outBase + (size_t)r * kK + k1] = (a1.x + a1.y) + (a1.z + a1.w);
            out[outBase + (size_t)r * kK + k2] = (a2.x + a2.y) + (a2.z + a2.w);
        }
    }
}

extern "C" void kernel_launch(void* const* d_in, const int* in_sizes, int n_in,
                              void* d_out, int out_size, void* d_ws, size_t ws_size,
                              hipStream_t stream) {
    const float* x  = (const float*)d_in[0];   // (B, I, J)
    const float* Wx = (const float*)d_in[1];   // (I, F)
    const float* Wy = (const float*)d_in[2];   // (J, F)
    const float* Wz = (const float*)d_in[3];   // (K, F)
    float* out = (float*)d_out;                // (B, I, K) f32

    const size_t wyBytes = 8192 * sizeof(uint4);   // 128 KiB
    const size_t wzBytes = 8192 * sizeof(uint4);   // 128 KiB

    if (ws_size >= wyBytes + wzBytes && d_ws != nullptr) {
        uint4* wyp = (uint4*)d_ws;
        uint4* wzp = (uint4*)((char*)d_ws + wyBytes);
        ge_prepack_all<<<dim3(128), 128, 0, stream>>>(Wy, Wz, wyp, wzp);
        ge_fused_mfma<<<dim3(kRows / 64), 256, 0, stream>>>(x, Wx, wyp, wzp, out);
    } else {
        gated_encoder_fused<<<dim3(kRows / 64), 256, 0, stream>>>(x, Wx, Wy, Wz, out);
    }
}